// Round 7
// baseline (532.171 us; speedup 1.0000x reference)
//
#include <hip/hip_runtime.h>
#include <cstdint>
#include <cstddef>

#define BB 4
#define CIN 256
#define HH 128
#define WW 128
#define NANCH (HH*WW*9)    // 147456
#define PRE_K 600
#define POST_K 100
#define NMS_T 0.7f
#define CAND_CAP 8192

typedef _Float16 f16x8 __attribute__((ext_vector_type(8)));
typedef float    f32x4 __attribute__((ext_vector_type(4)));

// ws layout (float units)
#define WS_SCORES 0                               // f32 [BB*NANCH]
#define WS_DELTAS (BB*NANCH)                      // f32 [BB*NANCH*4]
#define WS_WHI    (WS_DELTAS + BB*NANCH*4)        // fp16 [9][8][256][32]
#define WS_WLO    (WS_WHI + 9*256*128)
#define WS_HIST   (WS_WLO + 9*256*128)            // u32 [BB][2048]
#define WS_CCNT   (WS_HIST + 8192)                // u32 [16]
#define WS_CAND   (WS_CCNT + 16)                  // u64 [BB][8192]
#define WS_PHI    (WS_CAND + BB*CAND_CAP*2)       // fp16 hi plane [4][8][128][128][4x16B]
#define WS_PLANE_F 8388608
#define WS_PLO    (WS_PHI + WS_PLANE_F)
#define WS_ZERO   (WS_PLO + WS_PLANE_F)           // 64B zero page
#define WS_TOTAL_FULL (WS_ZERO + 16)
#define WS_TOTAL_MIN  WS_PHI

__device__ inline unsigned score_key(float f) {
    unsigned u = __float_as_uint(f);
    return (u & 0x80000000u) ? ~u : (u | 0x80000000u);
}

// ---------------------------------------------------------------------------
// Kernel 0 (merged prep): [0,prepBlocks) feature planes; [.., +256) weight
// split; [.., +33) zero histogram + candidate counters.
// ---------------------------------------------------------------------------
__global__ __launch_bounds__(256)
void prep_all(const float* __restrict__ feat, const float* __restrict__ convw,
              _Float16* __restrict__ pHi, _Float16* __restrict__ pLo,
              _Float16* __restrict__ whi, _Float16* __restrict__ wlo,
              float* __restrict__ zeroPg, unsigned* __restrict__ ghist,
              int prepBlocks)
{
    const int blk = blockIdx.x;
    if (blk < prepBlocks) {
        const int id = blk * 256 + threadIdx.x;      // 524288 = 4*8*128*128
        if (blk == 0 && threadIdx.x < 16) zeroPg[threadIdx.x] = 0.f;
        const int gx = id & 127;
        const int gy = (id >> 7) & 127;
        const int ck = (id >> 14) & 7;
        const int b  = id >> 17;
        const int g  = (((gx + 1) >> 1) & 1) | (((gy + 1) & 1) << 1);
        const float* fb = feat + ((size_t)(b*256 + ck*32) << 14) + (gy << 7) + gx;
        f16x8 gh[4], gl[4];
        #pragma unroll
        for (int icg = 0; icg < 4; ++icg)
            #pragma unroll
            for (int k = 0; k < 8; ++k) {
                const float v = fb[(size_t)(icg*8 + k) << 14] * 16.f;
                const _Float16 h = (_Float16)v;
                gh[icg][k] = h;
                gl[icg][k] = (_Float16)(v - (float)h);
            }
        char* Hc = (char*)pHi + (size_t)id * 64;
        char* Lc = (char*)pLo + (size_t)id * 64;
        #pragma unroll
        for (int icg = 0; icg < 4; ++icg) {
            const int p = icg ^ g;
            *(f16x8*)(Hc + p*16) = gh[icg];
            *(f16x8*)(Lc + p*16) = gl[icg];
        }
    } else if (blk < prepBlocks + 256) {
        const int g = (blk - prepBlocks) * 256 + threadIdx.x;  // oc*256+ic
        if (g >= 65536) return;
        const int oc = g >> 8, ic = g & 255;
        const int chunk = ic >> 5, icl = ic & 31;
        #pragma unroll
        for (int t = 0; t < 9; ++t) {
            const float v = convw[(size_t)g*9 + t] * 64.f;
            const _Float16 h = (_Float16)v;
            const _Float16 lo = (_Float16)(v - (float)h);
            const size_t o = (size_t)((t*8 + chunk)*256 + oc)*32 + icl;
            whi[o] = h;
            wlo[o] = lo;
        }
    } else {
        const int id = (blk - prepBlocks - 256) * 256 + threadIdx.x;
        if (id < 8208) ghist[id] = 0u;   // hist[8192] + ccnt[16]
    }
}

// ---------------------------------------------------------------------------
// Kernel 1: 3x3 conv 256ic->256oc via MFMA f16 hi/lo split (3-term fp32 emu)
// + bias + ReLU + fused 1x1 heads (head biases folded) + per-image coarse
// score histogram. Block: 512 thr / 8 waves; tile 256 oc x 256 px; grid 256.
// B-fragment LDS addresses fully factored: addr = rcbase[nf] + tapconst +
// xort[kx][ky&1] (xor bits are nf-independent); 9-tap loop fully unrolled so
// all selects are compile-time.
// ---------------------------------------------------------------------------
__global__ __launch_bounds__(512, 2)
void conv_mfma(const float* __restrict__ feat, const float* __restrict__ convb,
               const _Float16* __restrict__ whi, const _Float16* __restrict__ wlo,
               const float* __restrict__ clsw, const float* __restrict__ bboxw,
               const float* __restrict__ clsb, const float* __restrict__ bboxb,
               const _Float16* __restrict__ pHi, const _Float16* __restrict__ pLo,
               const float* __restrict__ zeroPg, unsigned* __restrict__ ghist,
               float* __restrict__ scores, float* __restrict__ deltas)
{
    // conv phase: halo hi[2] @0/21504, lo[2] @43008/64512; bias @86016 (1KB)
    // epilogue:   sW15 @0 (15360 B), sPart @15360 (61440 B), sHist @76800 (8KB)
    __shared__ __align__(16) unsigned char smem[87040];
    float* sBias = (float*)(smem + 86016);

    const int bid = blockIdx.x;                 // 256 = b(4) x ty(8) x tx(8)
    const int b  = bid >> 6;
    const int ty = (bid >> 3) & 7;
    const int tx = bid & 7;
    const int h0 = ty*16, c0 = tx*16;
    const int tid = threadIdx.x;
    const int w   = tid >> 6;                   // wave 0..7
    const int wm  = w >> 1;                     // oc quadrant
    const int wph = w & 1;                      // px half (rows 0-7 / 8-15)
    const int l  = tid & 63;
    const int q  = l >> 4;                      // lane k-group
    const int c  = l & 15;                      // lane row/col within fragment

    const float* featb = feat + (size_t)b*CIN*HH*WW;
    const int wOff = (wm*64 + c)*32 + q*8;      // A-slab per-lane offset (f16)

    if (tid < 256) sBias[tid] = convb[tid] * 1024.f;

    // ---- lane-constant B-address factors ----
    // Y(nf,ky) = wph*8 + (nf>>1)*2 + (c>>3) + ky ; X(nf,kx) = (nf&1)*8 + (c&7) + kx
    // (X>>1)&1 == (((c&7)+kx)>>1)&1  (nf-independent);  Y&1 == ((c>>3)+ky)&1
    int rcbase[8];
    #pragma unroll
    for (int nf = 0; nf < 8; ++nf) {
        const int by = wph*8 + (nf >> 1)*2 + (c >> 3);
        const int bxx = (nf & 1)*8 + (c & 7);
        rcbase[nf] = (by*18 + bxx)*64;
    }
    int xort[3][2];
    #pragma unroll
    for (int kx = 0; kx < 3; ++kx)
        #pragma unroll
        for (int kyp = 0; kyp < 2; ++kyp) {
            const int gxb = (((c & 7) + kx) >> 1) & 1;
            const int gyb = (((c >> 3) + kyp) & 1) << 1;
            xort[kx][kyp] = ((q ^ (gxb | gyb)) << 4);
        }

    // chunk-invariant stage descriptors
    int sdesc[3];
    #pragma unroll
    for (int it = 0; it < 3; ++it) {
        const int e = it*512 + tid;
        if (e < 1344) {                         // 1344 = 21*64, wave-uniform
            const int Yl = e / 72, rem = e - Yl*72;
            const int Xl = rem >> 2, p = rem & 3;
            const int gy = h0 - 1 + Yl, gx = c0 - 1 + Xl;
            sdesc[it] = (((unsigned)gy < 128u) && ((unsigned)gx < 128u))
                        ? ((((gy << 7) + gx) << 6) + (p << 4)) : -1;
        } else sdesc[it] = -2;
    }

    auto stage = [&](int ck, int buf) {
        unsigned char* hb = smem + buf*21504;
        unsigned char* lb = smem + 43008 + buf*21504;
        if (pHi) {
            const size_t pb = ((size_t)(b*8 + ck)) << 20;   // 1 MiB per (b,ck)
            #pragma unroll
            for (int pl = 0; pl < 2; ++pl) {
                const char* Ps = (const char*)(pl ? pLo : pHi) + pb;
                unsigned char* Pd = pl ? lb : hb;
                #pragma unroll
                for (int it = 0; it < 3; ++it) {
                    if (sdesc[it] != -2) {
                        const char* src = (sdesc[it] >= 0) ? Ps + sdesc[it]
                                                           : (const char*)zeroPg;
                        __builtin_amdgcn_global_load_lds(
                            (const __attribute__((address_space(1))) void*)src,
                            (__attribute__((address_space(3))) void*)(Pd + it*8192 + tid*16),
                            16, 0, 0);
                    }
                }
            }
        } else {
            const int ic0s = ck*32;
            for (int e = tid; e < 1296; e += 512) {
                const int icg = e / 324, s = e - icg*324;
                const int Y = s / 18, X = s - Y*18;
                const int gy = h0 - 1 + Y, gx = c0 - 1 + X;
                const int g = ((X >> 1) & 1) | ((Y & 1) << 1);
                const bool inb = ((unsigned)gy < 128u) && ((unsigned)gx < 128u);
                f16x8 hv, lv;
                #pragma unroll
                for (int k = 0; k < 8; ++k) {
                    float v = 0.f;
                    if (inb) v = featb[((size_t)(ic0s + icg*8 + k)*HH + gy)*WW + gx];
                    v *= 16.f;
                    const _Float16 h = (_Float16)v;
                    hv[k] = h;
                    lv[k] = (_Float16)(v - (float)h);
                }
                const int base = s*64 + ((icg ^ g) << 4);
                *(f16x8*)(hb + base) = hv;
                *(f16x8*)(lb + base) = lv;
            }
        }
    };

    stage(0, 0);
    __syncthreads();

    f32x4 acc[4][8];
    #pragma unroll
    for (int mf = 0; mf < 4; ++mf) {
        const f32x4 bv = *(const f32x4*)(sBias + (wm*64 + mf*16 + 4*q));
        #pragma unroll
        for (int nf = 0; nf < 8; ++nf) acc[mf][nf] = bv;
    }

    for (int chunk = 0; chunk < 8; ++chunk) {
        const int cur = chunk & 1;
        if (chunk + 1 < 8) stage(chunk + 1, cur ^ 1);   // async, overlaps t-loop
        const unsigned char* hb = smem + cur*21504;
        const unsigned char* lb = smem + 43008 + cur*21504;

        #pragma unroll
        for (int t = 0; t < 9; ++t) {
            const int ky = t / 3, kx = t - ky*3;
            const int tconst = (ky*18 + kx)*64;          // compile-time
            const _Float16* pWh = whi + (size_t)(t*8 + chunk)*8192 + wOff;
            const _Float16* pWl = wlo + (size_t)(t*8 + chunk)*8192 + wOff;
            f16x8 ah[4], al[4];
            #pragma unroll
            for (int mf = 0; mf < 4; ++mf) {
                ah[mf] = *(const f16x8*)(const void*)(pWh + mf*512);
                al[mf] = *(const f16x8*)(const void*)(pWl + mf*512);
            }
            #pragma unroll
            for (int nfh = 0; nfh < 2; ++nfh) {
                f16x8 bh[4], bl[4];
                #pragma unroll
                for (int j = 0; j < 4; ++j) {
                    const int nf = nfh*4 + j;
                    const int addr = rcbase[nf] + tconst + xort[kx][ky & 1];
                    bh[j] = *(const f16x8*)(hb + addr);
                    bl[j] = *(const f16x8*)(lb + addr);
                }
                #pragma unroll
                for (int mf = 0; mf < 4; ++mf)
                    #pragma unroll
                    for (int j = 0; j < 4; ++j) {
                        acc[mf][nfh*4+j] = __builtin_amdgcn_mfma_f32_16x16x32_f16(ah[mf], bh[j], acc[mf][nfh*4+j], 0, 0, 0);
                        acc[mf][nfh*4+j] = __builtin_amdgcn_mfma_f32_16x16x32_f16(ah[mf], bl[j], acc[mf][nfh*4+j], 0, 0, 0);
                        acc[mf][nfh*4+j] = __builtin_amdgcn_mfma_f32_16x16x32_f16(al[mf], bh[j], acc[mf][nfh*4+j], 0, 0, 0);
                    }
            }
        }
        __syncthreads();
    }

    // ---- epilogue: t = relu(acc)/1024, head fold, score histogram ----
    #pragma unroll
    for (int mf = 0; mf < 4; ++mf)
        #pragma unroll
        for (int nf = 0; nf < 8; ++nf)
            #pragma unroll
            for (int r = 0; r < 4; ++r)
                acc[mf][nf][r] = fmaxf(acc[mf][nf][r], 0.f) * 0.0009765625f;

    float*    sW15  = (float*)smem;              // [15][256] f32
    float*    sPart = (float*)(smem + 15360);    // [8 w][15][128 px] f32
    unsigned* sHist = (unsigned*)(smem + 76800); // [2048] u32

    for (int e = tid; e < 2048; e += 512) sHist[e] = 0u;

    for (int g = 0; g < 3; ++g) {
        __syncthreads();
        for (int e = tid; e < 3840; e += 512) {
            const int chl = e >> 8, o = e & 255;
            const int ch = g*15 + chl;
            sW15[e] = (ch < 9) ? clsw[ch*256 + o] : bboxw[(ch - 9)*256 + o];
        }
        __syncthreads();
        for (int chl = 0; chl < 15; ++chl) {
            f32x4 wv[4];
            #pragma unroll
            for (int mf = 0; mf < 4; ++mf)
                wv[mf] = *(const f32x4*)(sW15 + chl*256 + wm*64 + mf*16 + 4*q);
            float p[8];
            #pragma unroll
            for (int nf = 0; nf < 8; ++nf) {
                float s = 0.f;
                #pragma unroll
                for (int mf = 0; mf < 4; ++mf)
                    #pragma unroll
                    for (int r = 0; r < 4; ++r)
                        s += wv[mf][r] * acc[mf][nf][r];
                s += __shfl_xor(s, 16, 64);
                s += __shfl_xor(s, 32, 64);
                p[nf] = s;
            }
            const float v0 = (q == 0) ? p[0] : (q == 1) ? p[1] : (q == 2) ? p[2] : p[3];
            const float v1 = (q == 0) ? p[4] : (q == 1) ? p[5] : (q == 2) ? p[6] : p[7];
            sPart[(w*15 + chl)*128 + q*16 + c]      = v0;
            sPart[(w*15 + chl)*128 + 64 + q*16 + c] = v1;
        }
        __syncthreads();
        for (int e = tid; e < 3840; e += 512) {
            const int chl = e >> 8, pxg = e & 255;
            const int ph = pxg >> 7, pxl = pxg & 127;
            float s = 0.f;
            #pragma unroll
            for (int wmq = 0; wmq < 4; ++wmq)
                s += sPart[((wmq*2 + ph)*15 + chl)*128 + pxl];
            const int ch = g*15 + chl;
            s += (ch < 9) ? clsb[ch] : bboxb[ch - 9];
            const int nf = pxl >> 4, cc2 = pxl & 15;
            const int Y = ph*8 + (nf >> 1)*2 + (cc2 >> 3);
            const int X = (nf & 1)*8 + (cc2 & 7);
            const int gy = h0 + Y, gx = c0 + X;
            const int n4 = gy*WW + gx;
            if (ch < 9) {
                scores[(size_t)b*NANCH + n4*9 + ch] = s;
                atomicAdd(&sHist[score_key(s) >> 21], 1u);
            } else {
                const int cc = ch - 9;
                deltas[((size_t)b*NANCH + n4*9 + (cc >> 2))*4 + (cc & 3)] = s;
            }
        }
    }
    // merge block-local histogram (integer counts -> deterministic)
    for (int e = tid; e < 2048; e += 512) {
        const unsigned cv = sHist[e];
        if (cv) atomicAdd(&ghist[b*2048 + e], cv);
    }
}

// ---------------------------------------------------------------------------
// find_thresh: wave-0 parallel threshold search over a histogram.
// ---------------------------------------------------------------------------
__device__ inline void find_thresh(const unsigned* hist, int NB, unsigned target, unsigned* shv)
{
    const int tid = threadIdx.x;
    if (tid < 64) {
        const int gsz = NB >> 5;                  // 64 or 32
        unsigned gsum = 0;
        if (tid < 32)
            for (int k = 0; k < gsz; ++k)
                gsum += hist[tid*gsz + ((k + tid) & (gsz-1))];
        unsigned suf = gsum;
        #pragma unroll
        for (int d = 1; d < 32; d <<= 1) {
            const unsigned t = __shfl_down(suf, d, 64);
            if (tid + d < 32) suf += t;
        }
        const unsigned long long m = __ballot(tid < 32 && suf >= target);
        const int G = 63 - __clzll(m);
        unsigned caboveG = 0;
        { const unsigned t = __shfl(suf, G+1, 64); if (G < 31) caboveG = t; }
        unsigned h = 0;
        if (tid < gsz) h = hist[G*gsz + tid];
        unsigned wsuf = h;
        #pragma unroll
        for (int d = 1; d < 64; d <<= 1) {
            const unsigned t = __shfl_down(wsuf, d, 64);
            if (tid + d < gsz) wsuf += t;
        }
        const unsigned long long m2 = __ballot(tid < gsz && (caboveG + wsuf) >= target);
        const int L = 63 - __clzll(m2);
        if (tid == L) { shv[0] = (unsigned)(G*gsz + L); shv[1] = caboveG + wsuf - h; }
    }
}

// ---------------------------------------------------------------------------
// Kernel F: wide candidate filter. 256 blocks; block = (image, slice of 2304).
// Each block derives T1 from the global histogram, then compacts elements in
// bins >= T1 into the per-image candidate buffer (order-independent result).
// ---------------------------------------------------------------------------
__global__ __launch_bounds__(256)
void filter_kernel(const float* __restrict__ scores, const unsigned* __restrict__ ghist,
                   unsigned* __restrict__ ccnt, unsigned long long* __restrict__ cand)
{
    __shared__ unsigned h[2048];
    __shared__ unsigned shv[8];
    const int blk = blockIdx.x;         // 256 = b(4) x s(64)
    const int b = blk >> 6, s = blk & 63;
    const int tid = threadIdx.x;
    const unsigned* hb = ghist + b*2048;
    for (int e = tid; e < 2048; e += 256) h[e] = hb[e];
    __syncthreads();
    find_thresh(h, 2048, PRE_K, shv);
    __syncthreads();
    const unsigned T1 = shv[0];
    const unsigned C  = shv[1] + h[T1];     // count(>= T1) >= 600
    const float* si = scores + (size_t)b*NANCH + s*2304;
    if (C <= (unsigned)CAND_CAP) {
        #pragma unroll
        for (int k = 0; k < 9; ++k) {
            const int i = tid + k*256;
            const unsigned u = score_key(si[i]);
            if ((u >> 21) >= T1) {
                const unsigned p = atomicAdd(&ccnt[b], 1u);
                cand[(size_t)b*CAND_CAP + p] =
                    ((unsigned long long)(~u) << 32) | (unsigned)(s*2304 + i);
            }
        }
    } else if (s == 0 && tid == 0) {
        ccnt[b] = 0x7FFFFFFFu;              // overflow -> post fallback
    }
}

// ---------------------------------------------------------------------------
// Kernel 2 (post): exact top-600 via 3-pass radix over LDS-resident
// candidates (n <= 8192; provably identical to full-array radix since the
// candidate set contains ALL elements in bins >= T1), fallback full scan;
// then decode in LDS -> NMS -> keep-ordered top-100. Grid BB x 1024.
// ---------------------------------------------------------------------------
__device__ inline unsigned long long shfl_u64(unsigned long long v, int src) {
    const int lo = __shfl((int)(v & 0xffffffffull), src, 64);
    const int hi = __shfl((int)(v >> 32), src, 64);
    return ((unsigned long long)(unsigned)hi << 32) | (unsigned)lo;
}

__global__ __launch_bounds__(1024)
void post_kernel(const float* __restrict__ scores, const float* __restrict__ deltas,
                 const unsigned* __restrict__ ccnt, const unsigned long long* __restrict__ cand,
                 const int* __restrict__ imh, const int* __restrict__ imw,
                 float* __restrict__ out)
{
    __shared__ unsigned long long cnd[CAND_CAP];   // 64 KB
    __shared__ unsigned hist[2048];
    __shared__ unsigned long long arr[1024];
    __shared__ unsigned tiebuf[1024];
    __shared__ unsigned shv[8];
    __shared__ float bx[PRE_K][4];
    __shared__ unsigned long long mrow[PRE_K][10];
    __shared__ unsigned long long keepw[10];
    __shared__ unsigned wpfx[11];
    __shared__ int sel[POST_K];
    const int b = blockIdx.x, tid = threadIdx.x;
    const float* si = scores + (size_t)b*NANCH;

    const unsigned n = ccnt[b];
    const bool fast = (n <= (unsigned)CAND_CAP);

    // ---- shared radix macro-ish lambdas (scan source differs) ----
    if (fast) {
        for (int e = tid; e < CAND_CAP; e += 1024)
            cnd[e] = (e < (int)n) ? cand[(size_t)b*CAND_CAP + e] : ~0ull;
    }
    __syncthreads();

    // pass A
    for (int i = tid; i < 2048; i += 1024) hist[i] = 0;
    __syncthreads();
    if (fast) {
        for (int e = tid; e < (int)n; e += 1024) {
            const unsigned u = ~(unsigned)(cnd[e] >> 32);
            atomicAdd(&hist[u >> 21], 1u);
        }
    } else {
        for (int i = tid; i < NANCH; i += 1024)
            atomicAdd(&hist[score_key(si[i]) >> 21], 1u);
    }
    __syncthreads();
    find_thresh(hist, 2048, PRE_K, shv);
    __syncthreads();
    const unsigned T1 = shv[0], gtA = shv[1];
    __syncthreads();

    // pass B
    for (int i = tid; i < 2048; i += 1024) hist[i] = 0;
    __syncthreads();
    if (fast) {
        for (int e = tid; e < (int)n; e += 1024) {
            const unsigned u = ~(unsigned)(cnd[e] >> 32);
            if ((u >> 21) == T1) atomicAdd(&hist[(u >> 10) & 0x7FFu], 1u);
        }
    } else {
        for (int i = tid; i < NANCH; i += 1024) {
            const unsigned u = score_key(si[i]);
            if ((u >> 21) == T1) atomicAdd(&hist[(u >> 10) & 0x7FFu], 1u);
        }
    }
    __syncthreads();
    find_thresh(hist, 2048, PRE_K - gtA, shv);
    __syncthreads();
    const unsigned T2 = shv[0], gtB = shv[1];
    const unsigned top22 = (T1 << 11) | T2;
    __syncthreads();

    // pass C
    for (int i = tid; i < 1024; i += 1024) hist[i] = 0;
    __syncthreads();
    if (fast) {
        for (int e = tid; e < (int)n; e += 1024) {
            const unsigned u = ~(unsigned)(cnd[e] >> 32);
            if ((u >> 10) == top22) atomicAdd(&hist[u & 0x3FFu], 1u);
        }
    } else {
        for (int i = tid; i < NANCH; i += 1024) {
            const unsigned u = score_key(si[i]);
            if ((u >> 10) == top22) atomicAdd(&hist[u & 0x3FFu], 1u);
        }
    }
    __syncthreads();
    find_thresh(hist, 1024, PRE_K - gtA - gtB, shv);
    if (tid == 0) { shv[4] = 0; shv[5] = 0; }
    __syncthreads();
    const unsigned u_thr = (top22 << 10) | shv[0];
    const unsigned n_greater = gtA + gtB + shv[1];
    __syncthreads();

    // compact strictly-greater; collect ties
    if (fast) {
        for (int e = tid; e < (int)n; e += 1024) {
            const unsigned long long cv = cnd[e];
            const unsigned u = ~(unsigned)(cv >> 32);
            if (u > u_thr) {
                const unsigned p = atomicAdd(&shv[4], 1u);
                arr[p] = cv;
            } else if (u == u_thr) {
                const unsigned p = atomicAdd(&shv[5], 1u);
                if (p < 1024u) tiebuf[p] = (unsigned)cv;
            }
        }
    } else {
        for (int i = tid; i < NANCH; i += 1024) {
            const unsigned u = score_key(si[i]);
            if (u > u_thr) {
                const unsigned p = atomicAdd(&shv[4], 1u);
                arr[p] = ((unsigned long long)(~u) << 32) | (unsigned)i;
            } else if (u == u_thr) {
                const unsigned p = atomicAdd(&shv[5], 1u);
                if (p < 1024u) tiebuf[p] = (unsigned)i;
            }
        }
    }
    __syncthreads();
    const unsigned cnt_tie = (shv[5] > 1024u) ? 1024u : shv[5];
    if ((unsigned)tid >= cnt_tie) tiebuf[tid] = 0xFFFFFFFFu;

    for (unsigned k = 2; k <= 1024; k <<= 1)
        for (unsigned j = k >> 1; j > 0; j >>= 1) {
            __syncthreads();
            const unsigned i = (unsigned)tid, ixj = i ^ j;
            if (ixj > i) {
                const unsigned a = tiebuf[i], cc = tiebuf[ixj];
                if ((a > cc) == ((i & k) == 0)) { tiebuf[i] = cc; tiebuf[ixj] = a; }
            }
        }
    __syncthreads();
    const unsigned ties_needed = PRE_K - n_greater;
    if ((unsigned)tid < ties_needed)
        arr[n_greater + tid] = ((unsigned long long)(~u_thr) << 32) | tiebuf[tid];
    if (tid >= PRE_K) arr[tid] = ~0ull;

    for (unsigned k = 2; k <= 1024; k <<= 1)
        for (unsigned j = k >> 1; j > 0; j >>= 1) {
            __syncthreads();
            const unsigned i = (unsigned)tid, ixj = i ^ j;
            if (ixj > i) {
                const unsigned long long a = arr[i], cc = arr[ixj];
                if ((a > cc) == ((i & k) == 0)) { arr[i] = cc; arr[ixj] = a; }
            }
        }
    __syncthreads();

    // ===== decode the 600 selected boxes into LDS =====
    if (tid < PRE_K) {
        const unsigned idx = (unsigned)arr[tid];
        const int a   = (int)(idx % 9u);
        const int n4  = (int)(idx / 9u);
        const int hh_ = n4 >> 7;
        const int ww_ = n4 & 127;
        const int si_ = a / 3, ri = a % 3;
        const double sq = (ri == 0) ? 0.70710678118654752440 : ((ri == 1) ? 1.0 : 1.41421356237309504880);
        const double sc = (si_ == 0) ? 8.0 : ((si_ == 1) ? 16.0 : 32.0);
        const float half_w = (float)(16.0 * sc * sq * 0.5);
        const float half_h = (float)(16.0 * sc / sq * 0.5);
        const float shx = 16.f * (float)ww_;
        const float shy = 16.f * (float)hh_;
        const float x1a = shx - half_w, x2a = shx + half_w;
        const float y1a = shy - half_h, y2a = shy + half_h;
        const float aw = x2a - x1a, ah = y2a - y1a;
        const float acx = x1a + 0.5f*aw, acy = y1a + 0.5f*ah;
        const float* d = deltas + ((size_t)b*NANCH + idx) * 4;
        const float dx = d[0], dy = d[1], dw = d[2], dh = d[3];
        const float pcx = acx + dx*aw;
        const float pcy = acy + dy*ah;
        const float pw  = aw * expf(dw);
        const float ph  = ah * expf(dh);
        const float fw = (float)imw[0], fh = (float)imh[0];
        bx[tid][0] = fminf(fmaxf(pcx - 0.5f*pw, 0.f), fw);
        bx[tid][1] = fminf(fmaxf(pcy - 0.5f*ph, 0.f), fh);
        bx[tid][2] = fminf(fmaxf(pcx + 0.5f*pw, 0.f), fw);
        bx[tid][3] = fminf(fmaxf(pcy + 0.5f*ph, 0.f), fh);
    }
    __syncthreads();

    // ===== NMS =====
    for (int item = tid; item < PRE_K*10; item += 1024) {
        const int i  = item / 10;
        const int wj = item - i*10;
        unsigned long long m = 0ull;
        const int jbase = wj * 64;
        if (jbase + 63 > i) {
            const float xi1 = bx[i][0], yi1 = bx[i][1], xi2 = bx[i][2], yi2 = bx[i][3];
            const float ai = (xi2 - xi1) * (yi2 - yi1);
            for (int bit = 0; bit < 64; ++bit) {
                const int j = jbase + bit;
                if (j < PRE_K && j > i) {
                    const float xx1 = fmaxf(xi1, bx[j][0]);
                    const float yy1 = fmaxf(yi1, bx[j][1]);
                    const float xx2 = fminf(xi2, bx[j][2]);
                    const float yy2 = fminf(yi2, bx[j][3]);
                    const float inter = fmaxf(xx2 - xx1, 0.f) * fmaxf(yy2 - yy1, 0.f);
                    const float aj = (bx[j][2] - bx[j][0]) * (bx[j][3] - bx[j][1]);
                    const float iou = inter / (ai + aj - inter);
                    if (iou > NMS_T) m |= (1ull << bit);
                }
            }
        }
        mrow[i][wj] = m;
    }
    __syncthreads();

    if (tid < 64) {
        const int lane = tid;
        unsigned long long kwv;
        if (lane < 9)       kwv = ~0ull;
        else if (lane == 9) kwv = (1ull << (PRE_K - 576)) - 1;
        else                kwv = 0ull;
        for (int w = 0; w < 10; ++w) {
            const int base = w*64;
            const int nb = (w == 9) ? (PRE_K - 576) : 64;
            if (lane == w) {
                for (int bit = 0; bit < nb; ++bit) {
                    const unsigned long long mm = mrow[base + bit][w];
                    if ((kwv >> bit) & 1ull) kwv &= ~mm;
                }
            }
            const unsigned long long fw = shfl_u64(kwv, w);
            if (lane > w && lane < 10) {
                for (int bit = 0; bit < nb; ++bit) {
                    const unsigned long long mm = mrow[base + bit][lane];
                    if ((fw >> bit) & 1ull) kwv &= ~mm;
                }
            }
        }
        if (lane < 10) keepw[lane] = kwv;
    }
    __syncthreads();
    if (tid == 0) {
        unsigned ccount = 0;
        #pragma unroll
        for (int w = 0; w < 10; ++w) { wpfx[w] = ccount; ccount += (unsigned)__popcll(keepw[w]); }
        wpfx[10] = ccount;
    }
    if (tid < POST_K) sel[tid] = -1;
    __syncthreads();
    if (tid < PRE_K) {
        const int w = tid >> 6, bit = tid & 63;
        const unsigned long long kw = keepw[w];
        if ((kw >> bit) & 1ull) {
            const unsigned rank = wpfx[w] + (unsigned)__popcll(kw & ((1ull << bit) - 1ull));
            if (rank < POST_K) sel[rank] = tid;
        }
    }
    __syncthreads();
    if (tid < POST_K) {
        const int s_ = sel[tid];
        float o0 = 0.f, o1 = 0.f, o2 = 0.f, o3 = 0.f;
        if (s_ >= 0) { o0 = bx[s_][0]; o1 = bx[s_][1]; o2 = bx[s_][2]; o3 = bx[s_][3]; }
        float* o = out + (size_t)b*POST_K*4 + tid*4;
        o[0] = o0; o[1] = o1; o[2] = o2; o[3] = o3;
    }
}

// ---------------------------------------------------------------------------
extern "C" void kernel_launch(void* const* d_in, const int* in_sizes, int n_in,
                              void* d_out, int out_size, void* d_ws, size_t ws_size,
                              hipStream_t stream) {
    const float* feat  = (const float*)d_in[0];
    const float* convw = (const float*)d_in[1];
    const float* convb = (const float*)d_in[2];
    const float* clsw  = (const float*)d_in[3];
    const float* clsb  = (const float*)d_in[4];
    const float* bboxw = (const float*)d_in[5];
    const float* bboxb = (const float*)d_in[6];
    const int*   imh   = (const int*)d_in[7];
    const int*   imw   = (const int*)d_in[8];

    if (ws_size < (size_t)WS_TOTAL_MIN * sizeof(float)) return;
    const bool use_prep = ws_size >= (size_t)WS_TOTAL_FULL * sizeof(float);

    float*    scores = (float*)d_ws + WS_SCORES;
    float*    deltas = (float*)d_ws + WS_DELTAS;
    _Float16* whi    = (_Float16*)((float*)d_ws + WS_WHI);
    _Float16* wlo    = (_Float16*)((float*)d_ws + WS_WLO);
    unsigned* ghist  = (unsigned*)((float*)d_ws + WS_HIST);
    unsigned* ccnt   = (unsigned*)((float*)d_ws + WS_CCNT);
    unsigned long long* cand = (unsigned long long*)((float*)d_ws + WS_CAND);
    _Float16* pHi    = use_prep ? (_Float16*)((float*)d_ws + WS_PHI) : nullptr;
    _Float16* pLo    = use_prep ? (_Float16*)((float*)d_ws + WS_PLO) : nullptr;
    float*    zeroPg = use_prep ? ((float*)d_ws + WS_ZERO) : nullptr;
    float*    outp   = (float*)d_out;

    const int prepBlocks = use_prep ? 2048 : 0;
    prep_all<<<dim3(prepBlocks + 256 + 33), dim3(256), 0, stream>>>(
        feat, convw, pHi, pLo, whi, wlo, zeroPg, ghist, prepBlocks);
    conv_mfma<<<dim3(256), dim3(512), 0, stream>>>(feat, convb, whi, wlo, clsw, bboxw,
                                                   clsb, bboxb, pHi, pLo, zeroPg, ghist,
                                                   scores, deltas);
    filter_kernel<<<dim3(256), dim3(256), 0, stream>>>(scores, ghist, ccnt, cand);
    post_kernel<<<dim3(BB), dim3(1024), 0, stream>>>(scores, deltas, ccnt, cand,
                                                     imh, imw, outp);
}

// Round 8
// 448.407 us; speedup vs baseline: 1.1868x; 1.1868x over previous
//
#include <hip/hip_runtime.h>
#include <cstdint>
#include <cstddef>

#define BB 4
#define CIN 256
#define HH 128
#define WW 128
#define NANCH (HH*WW*9)    // 147456
#define PRE_K 600
#define POST_K 100
#define NMS_T 0.7f
#define CAND_CAP 8192

typedef _Float16 f16x8 __attribute__((ext_vector_type(8)));
typedef float    f32x4 __attribute__((ext_vector_type(4)));

// ws layout (float units)
#define WS_SCORES 0                               // f32 [BB*NANCH]
#define WS_DELTAS (BB*NANCH)                      // f32 [BB*NANCH*4]
#define WS_WHI    (WS_DELTAS + BB*NANCH*4)        // fp16 [9][8][256][32]
#define WS_WLO    (WS_WHI + 9*256*128)
#define WS_HIST   (WS_WLO + 9*256*128)            // u32 [BB][2048]
#define WS_CCNT   (WS_HIST + 8192)                // u32 [16]
#define WS_CAND   (WS_CCNT + 16)                  // u64 [BB][8192]
#define WS_PHI    (WS_CAND + BB*CAND_CAP*2)       // fp16 hi plane [4][8][128][128][4x16B]
#define WS_PLANE_F 8388608
#define WS_PLO    (WS_PHI + WS_PLANE_F)
#define WS_ZERO   (WS_PLO + WS_PLANE_F)           // 64B zero page
#define WS_TOTAL_FULL (WS_ZERO + 16)
#define WS_TOTAL_MIN  WS_PHI

__device__ inline unsigned score_key(float f) {
    unsigned u = __float_as_uint(f);
    return (u & 0x80000000u) ? ~u : (u | 0x80000000u);
}

// ---------------------------------------------------------------------------
// Kernel 0 (merged prep): [0,prepBlocks) feature planes; [.., +256) weight
// split; [.., +33) zero histogram + candidate counters.
// ---------------------------------------------------------------------------
__global__ __launch_bounds__(256)
void prep_all(const float* __restrict__ feat, const float* __restrict__ convw,
              _Float16* __restrict__ pHi, _Float16* __restrict__ pLo,
              _Float16* __restrict__ whi, _Float16* __restrict__ wlo,
              float* __restrict__ zeroPg, unsigned* __restrict__ ghist,
              int prepBlocks)
{
    const int blk = blockIdx.x;
    if (blk < prepBlocks) {
        const int id = blk * 256 + threadIdx.x;      // 524288 = 4*8*128*128
        if (blk == 0 && threadIdx.x < 16) zeroPg[threadIdx.x] = 0.f;
        const int gx = id & 127;
        const int gy = (id >> 7) & 127;
        const int ck = (id >> 14) & 7;
        const int b  = id >> 17;
        const int g  = (((gx + 1) >> 1) & 1) | (((gy + 1) & 1) << 1);
        const float* fb = feat + ((size_t)(b*256 + ck*32) << 14) + (gy << 7) + gx;
        f16x8 gh[4], gl[4];
        #pragma unroll
        for (int icg = 0; icg < 4; ++icg)
            #pragma unroll
            for (int k = 0; k < 8; ++k) {
                const float v = fb[(size_t)(icg*8 + k) << 14] * 16.f;
                const _Float16 h = (_Float16)v;
                gh[icg][k] = h;
                gl[icg][k] = (_Float16)(v - (float)h);
            }
        char* Hc = (char*)pHi + (size_t)id * 64;
        char* Lc = (char*)pLo + (size_t)id * 64;
        #pragma unroll
        for (int icg = 0; icg < 4; ++icg) {
            const int p = icg ^ g;
            *(f16x8*)(Hc + p*16) = gh[icg];
            *(f16x8*)(Lc + p*16) = gl[icg];
        }
    } else if (blk < prepBlocks + 256) {
        const int g = (blk - prepBlocks) * 256 + threadIdx.x;  // oc*256+ic
        if (g >= 65536) return;
        const int oc = g >> 8, ic = g & 255;
        const int chunk = ic >> 5, icl = ic & 31;
        #pragma unroll
        for (int t = 0; t < 9; ++t) {
            const float v = convw[(size_t)g*9 + t] * 64.f;
            const _Float16 h = (_Float16)v;
            const _Float16 lo = (_Float16)(v - (float)h);
            const size_t o = (size_t)((t*8 + chunk)*256 + oc)*32 + icl;
            whi[o] = h;
            wlo[o] = lo;
        }
    } else {
        const int id = (blk - prepBlocks - 256) * 256 + threadIdx.x;
        if (id < 8208) ghist[id] = 0u;   // hist[8192] + ccnt[16]
    }
}

// ---------------------------------------------------------------------------
// Kernel 1: 3x3 conv 256ic->256oc via MFMA f16 hi/lo split (3-term fp32 emu)
// + bias + ReLU + fused 1x1 heads (head biases folded) + per-image coarse
// score histogram. Block: 512 thr / 8 waves; tile 256 oc x 256 px; grid 256.
// NOTE: t-loop kept at "#pragma unroll 3" with inline address math — full
// unroll + precomputed address arrays caused scratch spills (round 7:
// WRITE_SIZE 12->108 MB, conv 210->310 us). Register budget is exactly
// 2 waves/SIMD (128 acc + 128 rest); don't widen live ranges here.
// ---------------------------------------------------------------------------
__global__ __launch_bounds__(512, 2)
void conv_mfma(const float* __restrict__ feat, const float* __restrict__ convb,
               const _Float16* __restrict__ whi, const _Float16* __restrict__ wlo,
               const float* __restrict__ clsw, const float* __restrict__ bboxw,
               const float* __restrict__ clsb, const float* __restrict__ bboxb,
               const _Float16* __restrict__ pHi, const _Float16* __restrict__ pLo,
               const float* __restrict__ zeroPg, unsigned* __restrict__ ghist,
               float* __restrict__ scores, float* __restrict__ deltas)
{
    // conv phase: halo hi[2] @0/21504, lo[2] @43008/64512; bias @86016 (1KB)
    // epilogue:   sW15 @0 (15360 B), sPart @15360 (61440 B), sHist @76800 (8KB)
    __shared__ __align__(16) unsigned char smem[87040];
    float* sBias = (float*)(smem + 86016);

    const int bid = blockIdx.x;                 // 256 = b(4) x ty(8) x tx(8)
    const int b  = bid >> 6;
    const int ty = (bid >> 3) & 7;
    const int tx = bid & 7;
    const int h0 = ty*16, c0 = tx*16;
    const int tid = threadIdx.x;
    const int w   = tid >> 6;                   // wave 0..7
    const int wm  = w >> 1;                     // oc quadrant
    const int wph = w & 1;                      // px half (rows 0-7 / 8-15)
    const int l  = tid & 63;
    const int q  = l >> 4;                      // lane k-group
    const int c  = l & 15;                      // lane row/col within fragment

    const float* featb = feat + (size_t)b*CIN*HH*WW;
    const int wOff = (wm*64 + c)*32 + q*8;      // A-slab per-lane offset (f16)

    if (tid < 256) sBias[tid] = convb[tid] * 1024.f;

    // chunk-invariant stage descriptors
    int sdesc[3];
    #pragma unroll
    for (int it = 0; it < 3; ++it) {
        const int e = it*512 + tid;
        if (e < 1344) {                         // 1344 = 21*64, wave-uniform
            const int Yl = e / 72, rem = e - Yl*72;
            const int Xl = rem >> 2, p = rem & 3;
            const int gy = h0 - 1 + Yl, gx = c0 - 1 + Xl;
            sdesc[it] = (((unsigned)gy < 128u) && ((unsigned)gx < 128u))
                        ? ((((gy << 7) + gx) << 6) + (p << 4)) : -1;
        } else sdesc[it] = -2;
    }

    auto stage = [&](int ck, int buf) {
        unsigned char* hb = smem + buf*21504;
        unsigned char* lb = smem + 43008 + buf*21504;
        if (pHi) {
            const size_t pb = ((size_t)(b*8 + ck)) << 20;   // 1 MiB per (b,ck)
            #pragma unroll
            for (int pl = 0; pl < 2; ++pl) {
                const char* Ps = (const char*)(pl ? pLo : pHi) + pb;
                unsigned char* Pd = pl ? lb : hb;
                #pragma unroll
                for (int it = 0; it < 3; ++it) {
                    if (sdesc[it] != -2) {
                        const char* src = (sdesc[it] >= 0) ? Ps + sdesc[it]
                                                           : (const char*)zeroPg;
                        __builtin_amdgcn_global_load_lds(
                            (const __attribute__((address_space(1))) void*)src,
                            (__attribute__((address_space(3))) void*)(Pd + it*8192 + tid*16),
                            16, 0, 0);
                    }
                }
            }
        } else {
            const int ic0s = ck*32;
            for (int e = tid; e < 1296; e += 512) {
                const int icg = e / 324, s = e - icg*324;
                const int Y = s / 18, X = s - Y*18;
                const int gy = h0 - 1 + Y, gx = c0 - 1 + X;
                const int g = ((X >> 1) & 1) | ((Y & 1) << 1);
                const bool inb = ((unsigned)gy < 128u) && ((unsigned)gx < 128u);
                f16x8 hv, lv;
                #pragma unroll
                for (int k = 0; k < 8; ++k) {
                    float v = 0.f;
                    if (inb) v = featb[((size_t)(ic0s + icg*8 + k)*HH + gy)*WW + gx];
                    v *= 16.f;
                    const _Float16 h = (_Float16)v;
                    hv[k] = h;
                    lv[k] = (_Float16)(v - (float)h);
                }
                const int base = s*64 + ((icg ^ g) << 4);
                *(f16x8*)(hb + base) = hv;
                *(f16x8*)(lb + base) = lv;
            }
        }
    };

    stage(0, 0);
    __syncthreads();

    f32x4 acc[4][8];
    #pragma unroll
    for (int mf = 0; mf < 4; ++mf) {
        const f32x4 bv = *(const f32x4*)(sBias + (wm*64 + mf*16 + 4*q));
        #pragma unroll
        for (int nf = 0; nf < 8; ++nf) acc[mf][nf] = bv;
    }

    for (int chunk = 0; chunk < 8; ++chunk) {
        const int cur = chunk & 1;
        if (chunk + 1 < 8) stage(chunk + 1, cur ^ 1);   // async, overlaps t-loop
        const unsigned char* hb = smem + cur*21504;
        const unsigned char* lb = smem + 43008 + cur*21504;

        #pragma unroll 3
        for (int t = 0; t < 9; ++t) {
            const int ky = t / 3, kx = t - ky*3;
            const _Float16* pWh = whi + (size_t)(t*8 + chunk)*8192 + wOff;
            const _Float16* pWl = wlo + (size_t)(t*8 + chunk)*8192 + wOff;
            f16x8 ah[4], al[4];
            #pragma unroll
            for (int mf = 0; mf < 4; ++mf) {
                ah[mf] = *(const f16x8*)(const void*)(pWh + mf*512);
                al[mf] = *(const f16x8*)(const void*)(pWl + mf*512);
            }
            #pragma unroll
            for (int nfh = 0; nfh < 2; ++nfh) {
                f16x8 bh[4], bl[4];
                #pragma unroll
                for (int j = 0; j < 4; ++j) {
                    const int nf = nfh*4 + j;
                    const int Y = wph*8 + (nf >> 1)*2 + (c >> 3) + ky;
                    const int X = (nf & 1)*8 + (c & 7) + kx;
                    const int g = ((X >> 1) & 1) | ((Y & 1) << 1);
                    const int addr = (Y*18 + X)*64 + ((q ^ g) << 4);
                    bh[j] = *(const f16x8*)(hb + addr);
                    bl[j] = *(const f16x8*)(lb + addr);
                }
                #pragma unroll
                for (int mf = 0; mf < 4; ++mf)
                    #pragma unroll
                    for (int j = 0; j < 4; ++j) {
                        acc[mf][nfh*4+j] = __builtin_amdgcn_mfma_f32_16x16x32_f16(ah[mf], bh[j], acc[mf][nfh*4+j], 0, 0, 0);
                        acc[mf][nfh*4+j] = __builtin_amdgcn_mfma_f32_16x16x32_f16(ah[mf], bl[j], acc[mf][nfh*4+j], 0, 0, 0);
                        acc[mf][nfh*4+j] = __builtin_amdgcn_mfma_f32_16x16x32_f16(al[mf], bh[j], acc[mf][nfh*4+j], 0, 0, 0);
                    }
            }
        }
        __syncthreads();
    }

    // ---- epilogue: t = relu(acc)/1024, head fold, score histogram ----
    #pragma unroll
    for (int mf = 0; mf < 4; ++mf)
        #pragma unroll
        for (int nf = 0; nf < 8; ++nf)
            #pragma unroll
            for (int r = 0; r < 4; ++r)
                acc[mf][nf][r] = fmaxf(acc[mf][nf][r], 0.f) * 0.0009765625f;

    float*    sW15  = (float*)smem;              // [15][256] f32
    float*    sPart = (float*)(smem + 15360);    // [8 w][15][128 px] f32
    unsigned* sHist = (unsigned*)(smem + 76800); // [2048] u32

    for (int e = tid; e < 2048; e += 512) sHist[e] = 0u;

    for (int g = 0; g < 3; ++g) {
        __syncthreads();
        for (int e = tid; e < 3840; e += 512) {
            const int chl = e >> 8, o = e & 255;
            const int ch = g*15 + chl;
            sW15[e] = (ch < 9) ? clsw[ch*256 + o] : bboxw[(ch - 9)*256 + o];
        }
        __syncthreads();
        for (int chl = 0; chl < 15; ++chl) {
            f32x4 wv[4];
            #pragma unroll
            for (int mf = 0; mf < 4; ++mf)
                wv[mf] = *(const f32x4*)(sW15 + chl*256 + wm*64 + mf*16 + 4*q);
            float p[8];
            #pragma unroll
            for (int nf = 0; nf < 8; ++nf) {
                float s = 0.f;
                #pragma unroll
                for (int mf = 0; mf < 4; ++mf)
                    #pragma unroll
                    for (int r = 0; r < 4; ++r)
                        s += wv[mf][r] * acc[mf][nf][r];
                s += __shfl_xor(s, 16, 64);
                s += __shfl_xor(s, 32, 64);
                p[nf] = s;
            }
            const float v0 = (q == 0) ? p[0] : (q == 1) ? p[1] : (q == 2) ? p[2] : p[3];
            const float v1 = (q == 0) ? p[4] : (q == 1) ? p[5] : (q == 2) ? p[6] : p[7];
            sPart[(w*15 + chl)*128 + q*16 + c]      = v0;
            sPart[(w*15 + chl)*128 + 64 + q*16 + c] = v1;
        }
        __syncthreads();
        for (int e = tid; e < 3840; e += 512) {
            const int chl = e >> 8, pxg = e & 255;
            const int ph = pxg >> 7, pxl = pxg & 127;
            float s = 0.f;
            #pragma unroll
            for (int wmq = 0; wmq < 4; ++wmq)
                s += sPart[((wmq*2 + ph)*15 + chl)*128 + pxl];
            const int ch = g*15 + chl;
            s += (ch < 9) ? clsb[ch] : bboxb[ch - 9];
            const int nf = pxl >> 4, cc2 = pxl & 15;
            const int Y = ph*8 + (nf >> 1)*2 + (cc2 >> 3);
            const int X = (nf & 1)*8 + (cc2 & 7);
            const int gy = h0 + Y, gx = c0 + X;
            const int n4 = gy*WW + gx;
            if (ch < 9) {
                scores[(size_t)b*NANCH + n4*9 + ch] = s;
                atomicAdd(&sHist[score_key(s) >> 21], 1u);
            } else {
                const int cc = ch - 9;
                deltas[((size_t)b*NANCH + n4*9 + (cc >> 2))*4 + (cc & 3)] = s;
            }
        }
    }
    // merge block-local histogram (integer counts -> deterministic)
    for (int e = tid; e < 2048; e += 512) {
        const unsigned cv = sHist[e];
        if (cv) atomicAdd(&ghist[b*2048 + e], cv);
    }
}

// ---------------------------------------------------------------------------
// find_thresh: wave-0 parallel threshold search over a histogram.
// ---------------------------------------------------------------------------
__device__ inline void find_thresh(const unsigned* hist, int NB, unsigned target, unsigned* shv)
{
    const int tid = threadIdx.x;
    if (tid < 64) {
        const int gsz = NB >> 5;                  // 64 or 32
        unsigned gsum = 0;
        if (tid < 32)
            for (int k = 0; k < gsz; ++k)
                gsum += hist[tid*gsz + ((k + tid) & (gsz-1))];
        unsigned suf = gsum;
        #pragma unroll
        for (int d = 1; d < 32; d <<= 1) {
            const unsigned t = __shfl_down(suf, d, 64);
            if (tid + d < 32) suf += t;
        }
        const unsigned long long m = __ballot(tid < 32 && suf >= target);
        const int G = 63 - __clzll(m);
        unsigned caboveG = 0;
        { const unsigned t = __shfl(suf, G+1, 64); if (G < 31) caboveG = t; }
        unsigned h = 0;
        if (tid < gsz) h = hist[G*gsz + tid];
        unsigned wsuf = h;
        #pragma unroll
        for (int d = 1; d < 64; d <<= 1) {
            const unsigned t = __shfl_down(wsuf, d, 64);
            if (tid + d < gsz) wsuf += t;
        }
        const unsigned long long m2 = __ballot(tid < gsz && (caboveG + wsuf) >= target);
        const int L = 63 - __clzll(m2);
        if (tid == L) { shv[0] = (unsigned)(G*gsz + L); shv[1] = caboveG + wsuf - h; }
    }
}

// ---------------------------------------------------------------------------
// Kernel F: wide candidate filter. 256 blocks; block = (image, slice of 2304).
// Each block derives T1 from the global histogram, then compacts elements in
// bins >= T1 into the per-image candidate buffer (order-independent result).
// ---------------------------------------------------------------------------
__global__ __launch_bounds__(256)
void filter_kernel(const float* __restrict__ scores, const unsigned* __restrict__ ghist,
                   unsigned* __restrict__ ccnt, unsigned long long* __restrict__ cand)
{
    __shared__ unsigned h[2048];
    __shared__ unsigned shv[8];
    const int blk = blockIdx.x;         // 256 = b(4) x s(64)
    const int b = blk >> 6, s = blk & 63;
    const int tid = threadIdx.x;
    const unsigned* hb = ghist + b*2048;
    for (int e = tid; e < 2048; e += 256) h[e] = hb[e];
    __syncthreads();
    find_thresh(h, 2048, PRE_K, shv);
    __syncthreads();
    const unsigned T1 = shv[0];
    const unsigned C  = shv[1] + h[T1];     // count(>= T1) >= 600
    const float* si = scores + (size_t)b*NANCH + s*2304;
    if (C <= (unsigned)CAND_CAP) {
        #pragma unroll
        for (int k = 0; k < 9; ++k) {
            const int i = tid + k*256;
            const unsigned u = score_key(si[i]);
            if ((u >> 21) >= T1) {
                const unsigned p = atomicAdd(&ccnt[b], 1u);
                cand[(size_t)b*CAND_CAP + p] =
                    ((unsigned long long)(~u) << 32) | (unsigned)(s*2304 + i);
            }
        }
    } else if (s == 0 && tid == 0) {
        ccnt[b] = 0x7FFFFFFFu;              // overflow -> post fallback
    }
}

// ---------------------------------------------------------------------------
// Kernel 2 (post): exact top-600 via 3-pass radix over LDS-resident
// candidates (n <= 8192; provably identical to full-array radix since the
// candidate set contains ALL elements in bins >= T1), fallback full scan;
// then decode in LDS -> NMS -> keep-ordered top-100. Grid BB x 1024.
// ---------------------------------------------------------------------------
__device__ inline unsigned long long shfl_u64(unsigned long long v, int src) {
    const int lo = __shfl((int)(v & 0xffffffffull), src, 64);
    const int hi = __shfl((int)(v >> 32), src, 64);
    return ((unsigned long long)(unsigned)hi << 32) | (unsigned)lo;
}

__global__ __launch_bounds__(1024)
void post_kernel(const float* __restrict__ scores, const float* __restrict__ deltas,
                 const unsigned* __restrict__ ccnt, const unsigned long long* __restrict__ cand,
                 const int* __restrict__ imh, const int* __restrict__ imw,
                 float* __restrict__ out)
{
    __shared__ unsigned long long cnd[CAND_CAP];   // 64 KB
    __shared__ unsigned hist[2048];
    __shared__ unsigned long long arr[1024];
    __shared__ unsigned tiebuf[1024];
    __shared__ unsigned shv[8];
    __shared__ float bx[PRE_K][4];
    __shared__ unsigned long long mrow[PRE_K][10];
    __shared__ unsigned long long keepw[10];
    __shared__ unsigned wpfx[11];
    __shared__ int sel[POST_K];
    const int b = blockIdx.x, tid = threadIdx.x;
    const float* si = scores + (size_t)b*NANCH;

    const unsigned n = ccnt[b];
    const bool fast = (n <= (unsigned)CAND_CAP);

    if (fast) {
        for (int e = tid; e < (int)n; e += 1024)
            cnd[e] = cand[(size_t)b*CAND_CAP + e];
    }
    __syncthreads();

    // pass A
    for (int i = tid; i < 2048; i += 1024) hist[i] = 0;
    __syncthreads();
    if (fast) {
        for (int e = tid; e < (int)n; e += 1024) {
            const unsigned u = ~(unsigned)(cnd[e] >> 32);
            atomicAdd(&hist[u >> 21], 1u);
        }
    } else {
        for (int i = tid; i < NANCH; i += 1024)
            atomicAdd(&hist[score_key(si[i]) >> 21], 1u);
    }
    __syncthreads();
    find_thresh(hist, 2048, PRE_K, shv);
    __syncthreads();
    const unsigned T1 = shv[0], gtA = shv[1];
    __syncthreads();

    // pass B
    for (int i = tid; i < 2048; i += 1024) hist[i] = 0;
    __syncthreads();
    if (fast) {
        for (int e = tid; e < (int)n; e += 1024) {
            const unsigned u = ~(unsigned)(cnd[e] >> 32);
            if ((u >> 21) == T1) atomicAdd(&hist[(u >> 10) & 0x7FFu], 1u);
        }
    } else {
        for (int i = tid; i < NANCH; i += 1024) {
            const unsigned u = score_key(si[i]);
            if ((u >> 21) == T1) atomicAdd(&hist[(u >> 10) & 0x7FFu], 1u);
        }
    }
    __syncthreads();
    find_thresh(hist, 2048, PRE_K - gtA, shv);
    __syncthreads();
    const unsigned T2 = shv[0], gtB = shv[1];
    const unsigned top22 = (T1 << 11) | T2;
    __syncthreads();

    // pass C
    for (int i = tid; i < 1024; i += 1024) hist[i] = 0;
    __syncthreads();
    if (fast) {
        for (int e = tid; e < (int)n; e += 1024) {
            const unsigned u = ~(unsigned)(cnd[e] >> 32);
            if ((u >> 10) == top22) atomicAdd(&hist[u & 0x3FFu], 1u);
        }
    } else {
        for (int i = tid; i < NANCH; i += 1024) {
            const unsigned u = score_key(si[i]);
            if ((u >> 10) == top22) atomicAdd(&hist[u & 0x3FFu], 1u);
        }
    }
    __syncthreads();
    find_thresh(hist, 1024, PRE_K - gtA - gtB, shv);
    if (tid == 0) { shv[4] = 0; shv[5] = 0; }
    __syncthreads();
    const unsigned u_thr = (top22 << 10) | shv[0];
    const unsigned n_greater = gtA + gtB + shv[1];
    __syncthreads();

    // compact strictly-greater; collect ties
    if (fast) {
        for (int e = tid; e < (int)n; e += 1024) {
            const unsigned long long cv = cnd[e];
            const unsigned u = ~(unsigned)(cv >> 32);
            if (u > u_thr) {
                const unsigned p = atomicAdd(&shv[4], 1u);
                arr[p] = cv;
            } else if (u == u_thr) {
                const unsigned p = atomicAdd(&shv[5], 1u);
                if (p < 1024u) tiebuf[p] = (unsigned)cv;
            }
        }
    } else {
        for (int i = tid; i < NANCH; i += 1024) {
            const unsigned u = score_key(si[i]);
            if (u > u_thr) {
                const unsigned p = atomicAdd(&shv[4], 1u);
                arr[p] = ((unsigned long long)(~u) << 32) | (unsigned)i;
            } else if (u == u_thr) {
                const unsigned p = atomicAdd(&shv[5], 1u);
                if (p < 1024u) tiebuf[p] = (unsigned)i;
            }
        }
    }
    __syncthreads();
    const unsigned cnt_tie = (shv[5] > 1024u) ? 1024u : shv[5];
    if ((unsigned)tid >= cnt_tie) tiebuf[tid] = 0xFFFFFFFFu;

    for (unsigned k = 2; k <= 1024; k <<= 1)
        for (unsigned j = k >> 1; j > 0; j >>= 1) {
            __syncthreads();
            const unsigned i = (unsigned)tid, ixj = i ^ j;
            if (ixj > i) {
                const unsigned a = tiebuf[i], cc = tiebuf[ixj];
                if ((a > cc) == ((i & k) == 0)) { tiebuf[i] = cc; tiebuf[ixj] = a; }
            }
        }
    __syncthreads();
    const unsigned ties_needed = PRE_K - n_greater;
    if ((unsigned)tid < ties_needed)
        arr[n_greater + tid] = ((unsigned long long)(~u_thr) << 32) | tiebuf[tid];
    if (tid >= PRE_K) arr[tid] = ~0ull;

    for (unsigned k = 2; k <= 1024; k <<= 1)
        for (unsigned j = k >> 1; j > 0; j >>= 1) {
            __syncthreads();
            const unsigned i = (unsigned)tid, ixj = i ^ j;
            if (ixj > i) {
                const unsigned long long a = arr[i], cc = arr[ixj];
                if ((a > cc) == ((i & k) == 0)) { arr[i] = cc; arr[ixj] = a; }
            }
        }
    __syncthreads();

    // ===== decode the 600 selected boxes into LDS =====
    if (tid < PRE_K) {
        const unsigned idx = (unsigned)arr[tid];
        const int a   = (int)(idx % 9u);
        const int n4  = (int)(idx / 9u);
        const int hh_ = n4 >> 7;
        const int ww_ = n4 & 127;
        const int si_ = a / 3, ri = a % 3;
        const double sq = (ri == 0) ? 0.70710678118654752440 : ((ri == 1) ? 1.0 : 1.41421356237309504880);
        const double sc = (si_ == 0) ? 8.0 : ((si_ == 1) ? 16.0 : 32.0);
        const float half_w = (float)(16.0 * sc * sq * 0.5);
        const float half_h = (float)(16.0 * sc / sq * 0.5);
        const float shx = 16.f * (float)ww_;
        const float shy = 16.f * (float)hh_;
        const float x1a = shx - half_w, x2a = shx + half_w;
        const float y1a = shy - half_h, y2a = shy + half_h;
        const float aw = x2a - x1a, ah = y2a - y1a;
        const float acx = x1a + 0.5f*aw, acy = y1a + 0.5f*ah;
        const float* d = deltas + ((size_t)b*NANCH + idx) * 4;
        const float dx = d[0], dy = d[1], dw = d[2], dh = d[3];
        const float pcx = acx + dx*aw;
        const float pcy = acy + dy*ah;
        const float pw  = aw * expf(dw);
        const float ph  = ah * expf(dh);
        const float fw = (float)imw[0], fh = (float)imh[0];
        bx[tid][0] = fminf(fmaxf(pcx - 0.5f*pw, 0.f), fw);
        bx[tid][1] = fminf(fmaxf(pcy - 0.5f*ph, 0.f), fh);
        bx[tid][2] = fminf(fmaxf(pcx + 0.5f*pw, 0.f), fw);
        bx[tid][3] = fminf(fmaxf(pcy + 0.5f*ph, 0.f), fh);
    }
    __syncthreads();

    // ===== NMS =====
    for (int item = tid; item < PRE_K*10; item += 1024) {
        const int i  = item / 10;
        const int wj = item - i*10;
        unsigned long long m = 0ull;
        const int jbase = wj * 64;
        if (jbase + 63 > i) {
            const float xi1 = bx[i][0], yi1 = bx[i][1], xi2 = bx[i][2], yi2 = bx[i][3];
            const float ai = (xi2 - xi1) * (yi2 - yi1);
            for (int bit = 0; bit < 64; ++bit) {
                const int j = jbase + bit;
                if (j < PRE_K && j > i) {
                    const float xx1 = fmaxf(xi1, bx[j][0]);
                    const float yy1 = fmaxf(yi1, bx[j][1]);
                    const float xx2 = fminf(xi2, bx[j][2]);
                    const float yy2 = fminf(yi2, bx[j][3]);
                    const float inter = fmaxf(xx2 - xx1, 0.f) * fmaxf(yy2 - yy1, 0.f);
                    const float aj = (bx[j][2] - bx[j][0]) * (bx[j][3] - bx[j][1]);
                    const float iou = inter / (ai + aj - inter);
                    if (iou > NMS_T) m |= (1ull << bit);
                }
            }
        }
        mrow[i][wj] = m;
    }
    __syncthreads();

    if (tid < 64) {
        const int lane = tid;
        unsigned long long kwv;
        if (lane < 9)       kwv = ~0ull;
        else if (lane == 9) kwv = (1ull << (PRE_K - 576)) - 1;
        else                kwv = 0ull;
        for (int w = 0; w < 10; ++w) {
            const int base = w*64;
            const int nb = (w == 9) ? (PRE_K - 576) : 64;
            if (lane == w) {
                for (int bit = 0; bit < nb; ++bit) {
                    const unsigned long long mm = mrow[base + bit][w];
                    if ((kwv >> bit) & 1ull) kwv &= ~mm;
                }
            }
            const unsigned long long fw = shfl_u64(kwv, w);
            if (lane > w && lane < 10) {
                for (int bit = 0; bit < nb; ++bit) {
                    const unsigned long long mm = mrow[base + bit][lane];
                    if ((fw >> bit) & 1ull) kwv &= ~mm;
                }
            }
        }
        if (lane < 10) keepw[lane] = kwv;
    }
    __syncthreads();
    if (tid == 0) {
        unsigned ccount = 0;
        #pragma unroll
        for (int w = 0; w < 10; ++w) { wpfx[w] = ccount; ccount += (unsigned)__popcll(keepw[w]); }
        wpfx[10] = ccount;
    }
    if (tid < POST_K) sel[tid] = -1;
    __syncthreads();
    if (tid < PRE_K) {
        const int w = tid >> 6, bit = tid & 63;
        const unsigned long long kw = keepw[w];
        if ((kw >> bit) & 1ull) {
            const unsigned rank = wpfx[w] + (unsigned)__popcll(kw & ((1ull << bit) - 1ull));
            if (rank < POST_K) sel[rank] = tid;
        }
    }
    __syncthreads();
    if (tid < POST_K) {
        const int s_ = sel[tid];
        float o0 = 0.f, o1 = 0.f, o2 = 0.f, o3 = 0.f;
        if (s_ >= 0) { o0 = bx[s_][0]; o1 = bx[s_][1]; o2 = bx[s_][2]; o3 = bx[s_][3]; }
        float* o = out + (size_t)b*POST_K*4 + tid*4;
        o[0] = o0; o[1] = o1; o[2] = o2; o[3] = o3;
    }
}

// ---------------------------------------------------------------------------
extern "C" void kernel_launch(void* const* d_in, const int* in_sizes, int n_in,
                              void* d_out, int out_size, void* d_ws, size_t ws_size,
                              hipStream_t stream) {
    const float* feat  = (const float*)d_in[0];
    const float* convw = (const float*)d_in[1];
    const float* convb = (const float*)d_in[2];
    const float* clsw  = (const float*)d_in[3];
    const float* clsb  = (const float*)d_in[4];
    const float* bboxw = (const float*)d_in[5];
    const float* bboxb = (const float*)d_in[6];
    const int*   imh   = (const int*)d_in[7];
    const int*   imw   = (const int*)d_in[8];

    if (ws_size < (size_t)WS_TOTAL_MIN * sizeof(float)) return;
    const bool use_prep = ws_size >= (size_t)WS_TOTAL_FULL * sizeof(float);

    float*    scores = (float*)d_ws + WS_SCORES;
    float*    deltas = (float*)d_ws + WS_DELTAS;
    _Float16* whi    = (_Float16*)((float*)d_ws + WS_WHI);
    _Float16* wlo    = (_Float16*)((float*)d_ws + WS_WLO);
    unsigned* ghist  = (unsigned*)((float*)d_ws + WS_HIST);
    unsigned* ccnt   = (unsigned*)((float*)d_ws + WS_CCNT);
    unsigned long long* cand = (unsigned long long*)((float*)d_ws + WS_CAND);
    _Float16* pHi    = use_prep ? (_Float16*)((float*)d_ws + WS_PHI) : nullptr;
    _Float16* pLo    = use_prep ? (_Float16*)((float*)d_ws + WS_PLO) : nullptr;
    float*    zeroPg = use_prep ? ((float*)d_ws + WS_ZERO) : nullptr;
    float*    outp   = (float*)d_out;

    const int prepBlocks = use_prep ? 2048 : 0;
    prep_all<<<dim3(prepBlocks + 256 + 33), dim3(256), 0, stream>>>(
        feat, convw, pHi, pLo, whi, wlo, zeroPg, ghist, prepBlocks);
    conv_mfma<<<dim3(256), dim3(512), 0, stream>>>(feat, convb, whi, wlo, clsw, bboxw,
                                                   clsb, bboxb, pHi, pLo, zeroPg, ghist,
                                                   scores, deltas);
    filter_kernel<<<dim3(256), dim3(256), 0, stream>>>(scores, ghist, ccnt, cand);
    post_kernel<<<dim3(BB), dim3(1024), 0, stream>>>(scores, deltas, ccnt, cand,
                                                     imh, imw, outp);
}

// Round 9
// 395.185 us; speedup vs baseline: 1.3466x; 1.1347x over previous
//
#include <hip/hip_runtime.h>
#include <cstdint>
#include <cstddef>

#define BB 4
#define CIN 256
#define HH 128
#define WW 128
#define NANCH (HH*WW*9)    // 147456
#define PRE_K 600
#define POST_K 100
#define NMS_T 0.7f
#define CAND_CAP 8192

typedef _Float16 f16x8 __attribute__((ext_vector_type(8)));
typedef float    f32x4 __attribute__((ext_vector_type(4)));

// ws layout (float units)
#define WS_SCORES 0                               // f32 [BB*NANCH]
#define WS_DELTAS (BB*NANCH)                      // f32 [BB*NANCH*4]
#define WS_WHI    (WS_DELTAS + BB*NANCH*4)        // fp16 [9][8][256][32]
#define WS_WLO    (WS_WHI + 9*256*128)
#define WS_HIST   (WS_WLO + 9*256*128)            // u32 [BB][2048]
#define WS_CCNT   (WS_HIST + 8192)                // u32 [16]
#define WS_CAND   (WS_CCNT + 16)                  // u64 [BB][8192]
#define WS_BOX6   (WS_CAND + BB*CAND_CAP*2)       // f32 [BB][600][4]
#define WS_MROW   (WS_BOX6 + BB*PRE_K*4)          // u64 [BB][600][10]
#define WS_PHI    (WS_MROW + BB*PRE_K*10*2)       // fp16 hi plane [4][8][128][128][4x16B]
#define WS_PLANE_F 8388608
#define WS_PLO    (WS_PHI + WS_PLANE_F)
#define WS_ZERO   (WS_PLO + WS_PLANE_F)           // 64B zero page
#define WS_TOTAL_FULL (WS_ZERO + 16)
#define WS_TOTAL_MIN  WS_PHI

__device__ inline unsigned score_key(float f) {
    unsigned u = __float_as_uint(f);
    return (u & 0x80000000u) ? ~u : (u | 0x80000000u);
}

// decode one box (exact float-op order shared by rank fast path and post fallback)
__device__ inline void decode_box(unsigned idx, const float* __restrict__ deltas,
                                  int b, float fw, float fh, float* o4)
{
    const int a   = (int)(idx % 9u);
    const int n4  = (int)(idx / 9u);
    const int hh_ = n4 >> 7;
    const int ww_ = n4 & 127;
    const int si_ = a / 3, ri = a % 3;
    const double sq = (ri == 0) ? 0.70710678118654752440 : ((ri == 1) ? 1.0 : 1.41421356237309504880);
    const double sc = (si_ == 0) ? 8.0 : ((si_ == 1) ? 16.0 : 32.0);
    const float half_w = (float)(16.0 * sc * sq * 0.5);
    const float half_h = (float)(16.0 * sc / sq * 0.5);
    const float shx = 16.f * (float)ww_;
    const float shy = 16.f * (float)hh_;
    const float x1a = shx - half_w, x2a = shx + half_w;
    const float y1a = shy - half_h, y2a = shy + half_h;
    const float aw = x2a - x1a, ah = y2a - y1a;
    const float acx = x1a + 0.5f*aw, acy = y1a + 0.5f*ah;
    const float* d = deltas + ((size_t)b*NANCH + idx) * 4;
    const float dx = d[0], dy = d[1], dw = d[2], dh = d[3];
    const float pcx = acx + dx*aw;
    const float pcy = acy + dy*ah;
    const float pw  = aw * expf(dw);
    const float ph  = ah * expf(dh);
    o4[0] = fminf(fmaxf(pcx - 0.5f*pw, 0.f), fw);
    o4[1] = fminf(fmaxf(pcy - 0.5f*ph, 0.f), fh);
    o4[2] = fminf(fmaxf(pcx + 0.5f*pw, 0.f), fw);
    o4[3] = fminf(fmaxf(pcy + 0.5f*ph, 0.f), fh);
}

// ---------------------------------------------------------------------------
// Kernel 0 (merged prep): [0,prepBlocks) feature planes; [.., +256) weight
// split; [.., +33) zero histogram + candidate counters.
// ---------------------------------------------------------------------------
__global__ __launch_bounds__(256)
void prep_all(const float* __restrict__ feat, const float* __restrict__ convw,
              _Float16* __restrict__ pHi, _Float16* __restrict__ pLo,
              _Float16* __restrict__ whi, _Float16* __restrict__ wlo,
              float* __restrict__ zeroPg, unsigned* __restrict__ ghist,
              int prepBlocks)
{
    const int blk = blockIdx.x;
    if (blk < prepBlocks) {
        const int id = blk * 256 + threadIdx.x;      // 524288 = 4*8*128*128
        if (blk == 0 && threadIdx.x < 16) zeroPg[threadIdx.x] = 0.f;
        const int gx = id & 127;
        const int gy = (id >> 7) & 127;
        const int ck = (id >> 14) & 7;
        const int b  = id >> 17;
        const int g  = (((gx + 1) >> 1) & 1) | (((gy + 1) & 1) << 1);
        const float* fb = feat + ((size_t)(b*256 + ck*32) << 14) + (gy << 7) + gx;
        f16x8 gh[4], gl[4];
        #pragma unroll
        for (int icg = 0; icg < 4; ++icg)
            #pragma unroll
            for (int k = 0; k < 8; ++k) {
                const float v = fb[(size_t)(icg*8 + k) << 14] * 16.f;
                const _Float16 h = (_Float16)v;
                gh[icg][k] = h;
                gl[icg][k] = (_Float16)(v - (float)h);
            }
        char* Hc = (char*)pHi + (size_t)id * 64;
        char* Lc = (char*)pLo + (size_t)id * 64;
        #pragma unroll
        for (int icg = 0; icg < 4; ++icg) {
            const int p = icg ^ g;
            *(f16x8*)(Hc + p*16) = gh[icg];
            *(f16x8*)(Lc + p*16) = gl[icg];
        }
    } else if (blk < prepBlocks + 256) {
        const int g = (blk - prepBlocks) * 256 + threadIdx.x;  // oc*256+ic
        if (g >= 65536) return;
        const int oc = g >> 8, ic = g & 255;
        const int chunk = ic >> 5, icl = ic & 31;
        #pragma unroll
        for (int t = 0; t < 9; ++t) {
            const float v = convw[(size_t)g*9 + t] * 64.f;
            const _Float16 h = (_Float16)v;
            const _Float16 lo = (_Float16)(v - (float)h);
            const size_t o = (size_t)((t*8 + chunk)*256 + oc)*32 + icl;
            whi[o] = h;
            wlo[o] = lo;
        }
    } else {
        const int id = (blk - prepBlocks - 256) * 256 + threadIdx.x;
        if (id < 8208) ghist[id] = 0u;   // hist[8192] + ccnt[16]
    }
}

// ---------------------------------------------------------------------------
// Kernel 1: 3x3 conv 256ic->256oc via MFMA f16 hi/lo split (3-term fp32 emu)
// + bias + ReLU + fused 1x1 heads (head biases folded) + per-image coarse
// score histogram. Block: 512 thr / 8 waves; tile 256 oc x 256 px; grid 256.
// NOTE: t-loop kept at "#pragma unroll 3" with inline address math — full
// unroll + precomputed address arrays caused scratch spills (round 7:
// WRITE_SIZE 12->108 MB, conv 210->310 us). Register budget is exactly
// 2 waves/SIMD (128 acc + 128 rest); don't widen live ranges here.
// ---------------------------------------------------------------------------
__global__ __launch_bounds__(512, 2)
void conv_mfma(const float* __restrict__ feat, const float* __restrict__ convb,
               const _Float16* __restrict__ whi, const _Float16* __restrict__ wlo,
               const float* __restrict__ clsw, const float* __restrict__ bboxw,
               const float* __restrict__ clsb, const float* __restrict__ bboxb,
               const _Float16* __restrict__ pHi, const _Float16* __restrict__ pLo,
               const float* __restrict__ zeroPg, unsigned* __restrict__ ghist,
               float* __restrict__ scores, float* __restrict__ deltas)
{
    // conv phase: halo hi[2] @0/21504, lo[2] @43008/64512; bias @86016 (1KB)
    // epilogue:   sW15 @0 (15360 B), sPart @15360 (61440 B), sHist @76800 (8KB)
    __shared__ __align__(16) unsigned char smem[87040];
    float* sBias = (float*)(smem + 86016);

    const int bid = blockIdx.x;                 // 256 = b(4) x ty(8) x tx(8)
    const int b  = bid >> 6;
    const int ty = (bid >> 3) & 7;
    const int tx = bid & 7;
    const int h0 = ty*16, c0 = tx*16;
    const int tid = threadIdx.x;
    const int w   = tid >> 6;                   // wave 0..7
    const int wm  = w >> 1;                     // oc quadrant
    const int wph = w & 1;                      // px half (rows 0-7 / 8-15)
    const int l  = tid & 63;
    const int q  = l >> 4;                      // lane k-group
    const int c  = l & 15;                      // lane row/col within fragment

    const float* featb = feat + (size_t)b*CIN*HH*WW;
    const int wOff = (wm*64 + c)*32 + q*8;      // A-slab per-lane offset (f16)

    if (tid < 256) sBias[tid] = convb[tid] * 1024.f;

    // chunk-invariant stage descriptors
    int sdesc[3];
    #pragma unroll
    for (int it = 0; it < 3; ++it) {
        const int e = it*512 + tid;
        if (e < 1344) {                         // 1344 = 21*64, wave-uniform
            const int Yl = e / 72, rem = e - Yl*72;
            const int Xl = rem >> 2, p = rem & 3;
            const int gy = h0 - 1 + Yl, gx = c0 - 1 + Xl;
            sdesc[it] = (((unsigned)gy < 128u) && ((unsigned)gx < 128u))
                        ? ((((gy << 7) + gx) << 6) + (p << 4)) : -1;
        } else sdesc[it] = -2;
    }

    auto stage = [&](int ck, int buf) {
        unsigned char* hb = smem + buf*21504;
        unsigned char* lb = smem + 43008 + buf*21504;
        if (pHi) {
            const size_t pb = ((size_t)(b*8 + ck)) << 20;   // 1 MiB per (b,ck)
            #pragma unroll
            for (int pl = 0; pl < 2; ++pl) {
                const char* Ps = (const char*)(pl ? pLo : pHi) + pb;
                unsigned char* Pd = pl ? lb : hb;
                #pragma unroll
                for (int it = 0; it < 3; ++it) {
                    if (sdesc[it] != -2) {
                        const char* src = (sdesc[it] >= 0) ? Ps + sdesc[it]
                                                           : (const char*)zeroPg;
                        __builtin_amdgcn_global_load_lds(
                            (const __attribute__((address_space(1))) void*)src,
                            (__attribute__((address_space(3))) void*)(Pd + it*8192 + tid*16),
                            16, 0, 0);
                    }
                }
            }
        } else {
            const int ic0s = ck*32;
            for (int e = tid; e < 1296; e += 512) {
                const int icg = e / 324, s = e - icg*324;
                const int Y = s / 18, X = s - Y*18;
                const int gy = h0 - 1 + Y, gx = c0 - 1 + X;
                const int g = ((X >> 1) & 1) | ((Y & 1) << 1);
                const bool inb = ((unsigned)gy < 128u) && ((unsigned)gx < 128u);
                f16x8 hv, lv;
                #pragma unroll
                for (int k = 0; k < 8; ++k) {
                    float v = 0.f;
                    if (inb) v = featb[((size_t)(ic0s + icg*8 + k)*HH + gy)*WW + gx];
                    v *= 16.f;
                    const _Float16 h = (_Float16)v;
                    hv[k] = h;
                    lv[k] = (_Float16)(v - (float)h);
                }
                const int base = s*64 + ((icg ^ g) << 4);
                *(f16x8*)(hb + base) = hv;
                *(f16x8*)(lb + base) = lv;
            }
        }
    };

    stage(0, 0);
    __syncthreads();

    f32x4 acc[4][8];
    #pragma unroll
    for (int mf = 0; mf < 4; ++mf) {
        const f32x4 bv = *(const f32x4*)(sBias + (wm*64 + mf*16 + 4*q));
        #pragma unroll
        for (int nf = 0; nf < 8; ++nf) acc[mf][nf] = bv;
    }

    for (int chunk = 0; chunk < 8; ++chunk) {
        const int cur = chunk & 1;
        if (chunk + 1 < 8) stage(chunk + 1, cur ^ 1);   // async, overlaps t-loop
        const unsigned char* hb = smem + cur*21504;
        const unsigned char* lb = smem + 43008 + cur*21504;

        #pragma unroll 3
        for (int t = 0; t < 9; ++t) {
            const int ky = t / 3, kx = t - ky*3;
            const _Float16* pWh = whi + (size_t)(t*8 + chunk)*8192 + wOff;
            const _Float16* pWl = wlo + (size_t)(t*8 + chunk)*8192 + wOff;
            f16x8 ah[4], al[4];
            #pragma unroll
            for (int mf = 0; mf < 4; ++mf) {
                ah[mf] = *(const f16x8*)(const void*)(pWh + mf*512);
                al[mf] = *(const f16x8*)(const void*)(pWl + mf*512);
            }
            #pragma unroll
            for (int nfh = 0; nfh < 2; ++nfh) {
                f16x8 bh[4], bl[4];
                #pragma unroll
                for (int j = 0; j < 4; ++j) {
                    const int nf = nfh*4 + j;
                    const int Y = wph*8 + (nf >> 1)*2 + (c >> 3) + ky;
                    const int X = (nf & 1)*8 + (c & 7) + kx;
                    const int g = ((X >> 1) & 1) | ((Y & 1) << 1);
                    const int addr = (Y*18 + X)*64 + ((q ^ g) << 4);
                    bh[j] = *(const f16x8*)(hb + addr);
                    bl[j] = *(const f16x8*)(lb + addr);
                }
                #pragma unroll
                for (int mf = 0; mf < 4; ++mf)
                    #pragma unroll
                    for (int j = 0; j < 4; ++j) {
                        acc[mf][nfh*4+j] = __builtin_amdgcn_mfma_f32_16x16x32_f16(ah[mf], bh[j], acc[mf][nfh*4+j], 0, 0, 0);
                        acc[mf][nfh*4+j] = __builtin_amdgcn_mfma_f32_16x16x32_f16(ah[mf], bl[j], acc[mf][nfh*4+j], 0, 0, 0);
                        acc[mf][nfh*4+j] = __builtin_amdgcn_mfma_f32_16x16x32_f16(al[mf], bh[j], acc[mf][nfh*4+j], 0, 0, 0);
                    }
            }
        }
        __syncthreads();
    }

    // ---- epilogue: t = relu(acc)/1024, head fold, score histogram ----
    #pragma unroll
    for (int mf = 0; mf < 4; ++mf)
        #pragma unroll
        for (int nf = 0; nf < 8; ++nf)
            #pragma unroll
            for (int r = 0; r < 4; ++r)
                acc[mf][nf][r] = fmaxf(acc[mf][nf][r], 0.f) * 0.0009765625f;

    float*    sW15  = (float*)smem;              // [15][256] f32
    float*    sPart = (float*)(smem + 15360);    // [8 w][15][128 px] f32
    unsigned* sHist = (unsigned*)(smem + 76800); // [2048] u32

    for (int e = tid; e < 2048; e += 512) sHist[e] = 0u;

    for (int g = 0; g < 3; ++g) {
        __syncthreads();
        for (int e = tid; e < 3840; e += 512) {
            const int chl = e >> 8, o = e & 255;
            const int ch = g*15 + chl;
            sW15[e] = (ch < 9) ? clsw[ch*256 + o] : bboxw[(ch - 9)*256 + o];
        }
        __syncthreads();
        for (int chl = 0; chl < 15; ++chl) {
            f32x4 wv[4];
            #pragma unroll
            for (int mf = 0; mf < 4; ++mf)
                wv[mf] = *(const f32x4*)(sW15 + chl*256 + wm*64 + mf*16 + 4*q);
            float p[8];
            #pragma unroll
            for (int nf = 0; nf < 8; ++nf) {
                float s = 0.f;
                #pragma unroll
                for (int mf = 0; mf < 4; ++mf)
                    #pragma unroll
                    for (int r = 0; r < 4; ++r)
                        s += wv[mf][r] * acc[mf][nf][r];
                s += __shfl_xor(s, 16, 64);
                s += __shfl_xor(s, 32, 64);
                p[nf] = s;
            }
            const float v0 = (q == 0) ? p[0] : (q == 1) ? p[1] : (q == 2) ? p[2] : p[3];
            const float v1 = (q == 0) ? p[4] : (q == 1) ? p[5] : (q == 2) ? p[6] : p[7];
            sPart[(w*15 + chl)*128 + q*16 + c]      = v0;
            sPart[(w*15 + chl)*128 + 64 + q*16 + c] = v1;
        }
        __syncthreads();
        for (int e = tid; e < 3840; e += 512) {
            const int chl = e >> 8, pxg = e & 255;
            const int ph = pxg >> 7, pxl = pxg & 127;
            float s = 0.f;
            #pragma unroll
            for (int wmq = 0; wmq < 4; ++wmq)
                s += sPart[((wmq*2 + ph)*15 + chl)*128 + pxl];
            const int ch = g*15 + chl;
            s += (ch < 9) ? clsb[ch] : bboxb[ch - 9];
            const int nf = pxl >> 4, cc2 = pxl & 15;
            const int Y = ph*8 + (nf >> 1)*2 + (cc2 >> 3);
            const int X = (nf & 1)*8 + (cc2 & 7);
            const int gy = h0 + Y, gx = c0 + X;
            const int n4 = gy*WW + gx;
            if (ch < 9) {
                scores[(size_t)b*NANCH + n4*9 + ch] = s;
                atomicAdd(&sHist[score_key(s) >> 21], 1u);
            } else {
                const int cc = ch - 9;
                deltas[((size_t)b*NANCH + n4*9 + (cc >> 2))*4 + (cc & 3)] = s;
            }
        }
    }
    // merge block-local histogram (integer counts -> deterministic)
    for (int e = tid; e < 2048; e += 512) {
        const unsigned cv = sHist[e];
        if (cv) atomicAdd(&ghist[b*2048 + e], cv);
    }
}

// ---------------------------------------------------------------------------
// find_thresh: wave-0 parallel threshold search over a histogram.
// ---------------------------------------------------------------------------
__device__ inline void find_thresh(const unsigned* hist, int NB, unsigned target, unsigned* shv)
{
    const int tid = threadIdx.x;
    if (tid < 64) {
        const int gsz = NB >> 5;                  // 64 or 32
        unsigned gsum = 0;
        if (tid < 32)
            for (int k = 0; k < gsz; ++k)
                gsum += hist[tid*gsz + ((k + tid) & (gsz-1))];
        unsigned suf = gsum;
        #pragma unroll
        for (int d = 1; d < 32; d <<= 1) {
            const unsigned t = __shfl_down(suf, d, 64);
            if (tid + d < 32) suf += t;
        }
        const unsigned long long m = __ballot(tid < 32 && suf >= target);
        const int G = 63 - __clzll(m);
        unsigned caboveG = 0;
        { const unsigned t = __shfl(suf, G+1, 64); if (G < 31) caboveG = t; }
        unsigned h = 0;
        if (tid < gsz) h = hist[G*gsz + tid];
        unsigned wsuf = h;
        #pragma unroll
        for (int d = 1; d < 64; d <<= 1) {
            const unsigned t = __shfl_down(wsuf, d, 64);
            if (tid + d < gsz) wsuf += t;
        }
        const unsigned long long m2 = __ballot(tid < gsz && (caboveG + wsuf) >= target);
        const int L = 63 - __clzll(m2);
        if (tid == L) { shv[0] = (unsigned)(G*gsz + L); shv[1] = caboveG + wsuf - h; }
    }
}

// ---------------------------------------------------------------------------
// Kernel F: wide candidate filter. 256 blocks; block = (image, slice of 2304).
// ---------------------------------------------------------------------------
__global__ __launch_bounds__(256)
void filter_kernel(const float* __restrict__ scores, const unsigned* __restrict__ ghist,
                   unsigned* __restrict__ ccnt, unsigned long long* __restrict__ cand)
{
    __shared__ unsigned h[2048];
    __shared__ unsigned shv[8];
    const int blk = blockIdx.x;         // 256 = b(4) x s(64)
    const int b = blk >> 6, s = blk & 63;
    const int tid = threadIdx.x;
    const unsigned* hb = ghist + b*2048;
    for (int e = tid; e < 2048; e += 256) h[e] = hb[e];
    __syncthreads();
    find_thresh(h, 2048, PRE_K, shv);
    __syncthreads();
    const unsigned T1 = shv[0];
    const unsigned C  = shv[1] + h[T1];     // count(>= T1) >= 600
    const float* si = scores + (size_t)b*NANCH + s*2304;
    if (C <= (unsigned)CAND_CAP) {
        #pragma unroll
        for (int k = 0; k < 9; ++k) {
            const int i = tid + k*256;
            const unsigned u = score_key(si[i]);
            if ((u >> 21) >= T1) {
                const unsigned p = atomicAdd(&ccnt[b], 1u);
                cand[(size_t)b*CAND_CAP + p] =
                    ((unsigned long long)(~u) << 32) | (unsigned)(s*2304 + i);
            }
        }
    } else if (s == 0 && tid == 0) {
        ccnt[b] = 0x7FFFFFFFu;              // overflow -> post fallback
    }
}

// ---------------------------------------------------------------------------
// Kernel R: wide rank-by-counting selection + decode. Keys (~u)<<32|idx are
// unique -> rank = #{cv2 < cv} is exact score-desc/index-asc order. Threads
// with rank < 600 decode their box straight into boxes600[b][rank].
// Grid 4 images x 32 slices of 256.
// ---------------------------------------------------------------------------
__global__ __launch_bounds__(256)
void rank_kernel(const unsigned* __restrict__ ccnt, const unsigned long long* __restrict__ cand,
                 const float* __restrict__ deltas,
                 const int* __restrict__ imh, const int* __restrict__ imw,
                 float* __restrict__ boxes6)
{
    __shared__ unsigned long long cnd[CAND_CAP];   // 64 KB
    const int blk = blockIdx.x;          // 128 = b(4) x s(32)
    const int b = blk >> 5, s = blk & 31;
    const int tid = threadIdx.x;
    const unsigned n = ccnt[b];
    if (n > (unsigned)CAND_CAP) return;            // fallback handled in post
    const int e0 = s*256;
    if ((unsigned)e0 >= n) return;
    for (int e = tid; e < (int)n; e += 256)
        cnd[e] = cand[(size_t)b*CAND_CAP + e];
    __syncthreads();
    const int e = e0 + tid;
    if (e >= (int)n) return;
    const unsigned long long cv = cnd[e];
    unsigned rank = 0;
    for (int e2 = 0; e2 < (int)n; ++e2)
        rank += (cnd[e2] < cv) ? 1u : 0u;
    if (rank < PRE_K) {
        float o4[4];
        decode_box((unsigned)cv, deltas, b, (float)imw[0], (float)imh[0], o4);
        float* o = boxes6 + ((size_t)b*PRE_K + rank)*4;
        o[0] = o4[0]; o[1] = o4[1]; o[2] = o4[2]; o[3] = o4[3];
    }
}

// ---------------------------------------------------------------------------
// Kernel M: wide NMS suppression-mask build. Grid 4 images x 10 row-groups
// (60 rows x 10 words each). Writes gmrow[b][600][10].
// ---------------------------------------------------------------------------
__global__ __launch_bounds__(256)
void nmsmask_kernel(const unsigned* __restrict__ ccnt, const float* __restrict__ boxes6,
                    unsigned long long* __restrict__ gmrow)
{
    __shared__ float bx[PRE_K][4];
    const int blk = blockIdx.x;          // 40 = b(4) x rg(10)
    const int b = blk / 10, rg = blk - b*10;
    const int tid = threadIdx.x;
    const unsigned n = ccnt[b];
    if (n > (unsigned)CAND_CAP) return;            // fallback handled in post
    for (int e = tid; e < PRE_K*4; e += 256)
        bx[e >> 2][e & 3] = boxes6[(size_t)b*PRE_K*4 + e];
    __syncthreads();
    for (int item = tid; item < 600; item += 256) {  // 60 rows x 10 words
        const int i  = rg*60 + item/10;
        const int wj = item - (item/10)*10;
        unsigned long long m = 0ull;
        const int jbase = wj * 64;
        if (jbase + 63 > i) {
            const float xi1 = bx[i][0], yi1 = bx[i][1], xi2 = bx[i][2], yi2 = bx[i][3];
            const float ai = (xi2 - xi1) * (yi2 - yi1);
            for (int bit = 0; bit < 64; ++bit) {
                const int j = jbase + bit;
                if (j < PRE_K && j > i) {
                    const float xx1 = fmaxf(xi1, bx[j][0]);
                    const float yy1 = fmaxf(yi1, bx[j][1]);
                    const float xx2 = fminf(xi2, bx[j][2]);
                    const float yy2 = fminf(yi2, bx[j][3]);
                    const float inter = fmaxf(xx2 - xx1, 0.f) * fmaxf(yy2 - yy1, 0.f);
                    const float aj = (bx[j][2] - bx[j][0]) * (bx[j][3] - bx[j][1]);
                    const float iou = inter / (ai + aj - inter);
                    if (iou > NMS_T) m |= (1ull << bit);
                }
            }
        }
        gmrow[((size_t)b*PRE_K + i)*10 + wj] = m;
    }
}

// ---------------------------------------------------------------------------
// Kernel 2 (post): fast path = load precomputed boxes+mask, serial keep-scan,
// compact, write top-100. Fallback (n > CAND_CAP, never on bench data) =
// full exact 3-pass radix over global scores + sorts + decode + mask.
// ---------------------------------------------------------------------------
__device__ inline unsigned long long shfl_u64(unsigned long long v, int src) {
    const int lo = __shfl((int)(v & 0xffffffffull), src, 64);
    const int hi = __shfl((int)(v >> 32), src, 64);
    return ((unsigned long long)(unsigned)hi << 32) | (unsigned)lo;
}

__global__ __launch_bounds__(1024)
void post_kernel(const float* __restrict__ scores, const float* __restrict__ deltas,
                 const unsigned* __restrict__ ccnt,
                 const float* __restrict__ boxes6, const unsigned long long* __restrict__ gmrow,
                 const int* __restrict__ imh, const int* __restrict__ imw,
                 float* __restrict__ out)
{
    __shared__ unsigned hist[2048];
    __shared__ unsigned long long arr[1024];
    __shared__ unsigned tiebuf[1024];
    __shared__ unsigned shv[8];
    __shared__ float bx[PRE_K][4];
    __shared__ unsigned long long mrow[PRE_K][10];
    __shared__ unsigned long long keepw[10];
    __shared__ unsigned wpfx[11];
    __shared__ int sel[POST_K];
    const int b = blockIdx.x, tid = threadIdx.x;
    const float* si = scores + (size_t)b*NANCH;

    const unsigned n = ccnt[b];
    const bool fast = (n <= (unsigned)CAND_CAP);

    if (fast) {
        // ===== fast path: everything precomputed by rank/nmsmask =====
        for (int e = tid; e < PRE_K*4; e += 1024)
            bx[e >> 2][e & 3] = boxes6[(size_t)b*PRE_K*4 + e];
        for (int e = tid; e < PRE_K*10; e += 1024)
            mrow[e/10][e - (e/10)*10] = gmrow[(size_t)b*PRE_K*10 + e];
        __syncthreads();
    } else {
        // ===== fallback: exact full-scan selection =====
        for (int i = tid; i < 2048; i += 1024) hist[i] = 0;
        __syncthreads();
        for (int i = tid; i < NANCH; i += 1024)
            atomicAdd(&hist[score_key(si[i]) >> 21], 1u);
        __syncthreads();
        find_thresh(hist, 2048, PRE_K, shv);
        __syncthreads();
        const unsigned T1 = shv[0], gtA = shv[1];
        __syncthreads();

        for (int i = tid; i < 2048; i += 1024) hist[i] = 0;
        __syncthreads();
        for (int i = tid; i < NANCH; i += 1024) {
            const unsigned u = score_key(si[i]);
            if ((u >> 21) == T1) atomicAdd(&hist[(u >> 10) & 0x7FFu], 1u);
        }
        __syncthreads();
        find_thresh(hist, 2048, PRE_K - gtA, shv);
        __syncthreads();
        const unsigned T2 = shv[0], gtB = shv[1];
        const unsigned top22 = (T1 << 11) | T2;
        __syncthreads();

        for (int i = tid; i < 1024; i += 1024) hist[i] = 0;
        __syncthreads();
        for (int i = tid; i < NANCH; i += 1024) {
            const unsigned u = score_key(si[i]);
            if ((u >> 10) == top22) atomicAdd(&hist[u & 0x3FFu], 1u);
        }
        __syncthreads();
        find_thresh(hist, 1024, PRE_K - gtA - gtB, shv);
        if (tid == 0) { shv[4] = 0; shv[5] = 0; }
        __syncthreads();
        const unsigned u_thr = (top22 << 10) | shv[0];
        const unsigned n_greater = gtA + gtB + shv[1];
        __syncthreads();

        for (int i = tid; i < NANCH; i += 1024) {
            const unsigned u = score_key(si[i]);
            if (u > u_thr) {
                const unsigned p = atomicAdd(&shv[4], 1u);
                arr[p] = ((unsigned long long)(~u) << 32) | (unsigned)i;
            } else if (u == u_thr) {
                const unsigned p = atomicAdd(&shv[5], 1u);
                if (p < 1024u) tiebuf[p] = (unsigned)i;
            }
        }
        __syncthreads();
        const unsigned cnt_tie = (shv[5] > 1024u) ? 1024u : shv[5];
        if ((unsigned)tid >= cnt_tie) tiebuf[tid] = 0xFFFFFFFFu;

        for (unsigned k = 2; k <= 1024; k <<= 1)
            for (unsigned j = k >> 1; j > 0; j >>= 1) {
                __syncthreads();
                const unsigned i = (unsigned)tid, ixj = i ^ j;
                if (ixj > i) {
                    const unsigned a = tiebuf[i], cc = tiebuf[ixj];
                    if ((a > cc) == ((i & k) == 0)) { tiebuf[i] = cc; tiebuf[ixj] = a; }
                }
            }
        __syncthreads();
        const unsigned ties_needed = PRE_K - n_greater;
        if ((unsigned)tid < ties_needed)
            arr[n_greater + tid] = ((unsigned long long)(~u_thr) << 32) | tiebuf[tid];
        if (tid >= PRE_K) arr[tid] = ~0ull;

        for (unsigned k = 2; k <= 1024; k <<= 1)
            for (unsigned j = k >> 1; j > 0; j >>= 1) {
                __syncthreads();
                const unsigned i = (unsigned)tid, ixj = i ^ j;
                if (ixj > i) {
                    const unsigned long long a = arr[i], cc = arr[ixj];
                    if ((a > cc) == ((i & k) == 0)) { arr[i] = cc; arr[ixj] = a; }
                }
            }
        __syncthreads();

        // decode into LDS
        if (tid < PRE_K) {
            float o4[4];
            decode_box((unsigned)arr[tid], deltas, b, (float)imw[0], (float)imh[0], o4);
            bx[tid][0] = o4[0]; bx[tid][1] = o4[1]; bx[tid][2] = o4[2]; bx[tid][3] = o4[3];
        }
        __syncthreads();

        // mask build
        for (int item = tid; item < PRE_K*10; item += 1024) {
            const int i  = item / 10;
            const int wj = item - i*10;
            unsigned long long m = 0ull;
            const int jbase = wj * 64;
            if (jbase + 63 > i) {
                const float xi1 = bx[i][0], yi1 = bx[i][1], xi2 = bx[i][2], yi2 = bx[i][3];
                const float ai = (xi2 - xi1) * (yi2 - yi1);
                for (int bit = 0; bit < 64; ++bit) {
                    const int j = jbase + bit;
                    if (j < PRE_K && j > i) {
                        const float xx1 = fmaxf(xi1, bx[j][0]);
                        const float yy1 = fmaxf(yi1, bx[j][1]);
                        const float xx2 = fminf(xi2, bx[j][2]);
                        const float yy2 = fminf(yi2, bx[j][3]);
                        const float inter = fmaxf(xx2 - xx1, 0.f) * fmaxf(yy2 - yy1, 0.f);
                        const float aj = (bx[j][2] - bx[j][0]) * (bx[j][3] - bx[j][1]);
                        const float iou = inter / (ai + aj - inter);
                        if (iou > NMS_T) m |= (1ull << bit);
                    }
                }
            }
            mrow[i][wj] = m;
        }
        __syncthreads();
    }

    // ===== serial keep-scan (wave 0), compaction, output =====
    if (tid < 64) {
        const int lane = tid;
        unsigned long long kwv;
        if (lane < 9)       kwv = ~0ull;
        else if (lane == 9) kwv = (1ull << (PRE_K - 576)) - 1;
        else                kwv = 0ull;
        for (int w = 0; w < 10; ++w) {
            const int base = w*64;
            const int nb = (w == 9) ? (PRE_K - 576) : 64;
            if (lane == w) {
                for (int bit = 0; bit < nb; ++bit) {
                    const unsigned long long mm = mrow[base + bit][w];
                    if ((kwv >> bit) & 1ull) kwv &= ~mm;
                }
            }
            const unsigned long long fw = shfl_u64(kwv, w);
            if (lane > w && lane < 10) {
                for (int bit = 0; bit < nb; ++bit) {
                    const unsigned long long mm = mrow[base + bit][lane];
                    if ((fw >> bit) & 1ull) kwv &= ~mm;
                }
            }
        }
        if (lane < 10) keepw[lane] = kwv;
    }
    __syncthreads();
    if (tid == 0) {
        unsigned ccount = 0;
        #pragma unroll
        for (int w = 0; w < 10; ++w) { wpfx[w] = ccount; ccount += (unsigned)__popcll(keepw[w]); }
        wpfx[10] = ccount;
    }
    if (tid < POST_K) sel[tid] = -1;
    __syncthreads();
    if (tid < PRE_K) {
        const int w = tid >> 6, bit = tid & 63;
        const unsigned long long kw = keepw[w];
        if ((kw >> bit) & 1ull) {
            const unsigned rank = wpfx[w] + (unsigned)__popcll(kw & ((1ull << bit) - 1ull));
            if (rank < POST_K) sel[rank] = tid;
        }
    }
    __syncthreads();
    if (tid < POST_K) {
        const int s_ = sel[tid];
        float o0 = 0.f, o1 = 0.f, o2 = 0.f, o3 = 0.f;
        if (s_ >= 0) { o0 = bx[s_][0]; o1 = bx[s_][1]; o2 = bx[s_][2]; o3 = bx[s_][3]; }
        float* o = out + (size_t)b*POST_K*4 + tid*4;
        o[0] = o0; o[1] = o1; o[2] = o2; o[3] = o3;
    }
}

// ---------------------------------------------------------------------------
extern "C" void kernel_launch(void* const* d_in, const int* in_sizes, int n_in,
                              void* d_out, int out_size, void* d_ws, size_t ws_size,
                              hipStream_t stream) {
    const float* feat  = (const float*)d_in[0];
    const float* convw = (const float*)d_in[1];
    const float* convb = (const float*)d_in[2];
    const float* clsw  = (const float*)d_in[3];
    const float* clsb  = (const float*)d_in[4];
    const float* bboxw = (const float*)d_in[5];
    const float* bboxb = (const float*)d_in[6];
    const int*   imh   = (const int*)d_in[7];
    const int*   imw   = (const int*)d_in[8];

    if (ws_size < (size_t)WS_TOTAL_MIN * sizeof(float)) return;
    const bool use_prep = ws_size >= (size_t)WS_TOTAL_FULL * sizeof(float);

    float*    scores = (float*)d_ws + WS_SCORES;
    float*    deltas = (float*)d_ws + WS_DELTAS;
    _Float16* whi    = (_Float16*)((float*)d_ws + WS_WHI);
    _Float16* wlo    = (_Float16*)((float*)d_ws + WS_WLO);
    unsigned* ghist  = (unsigned*)((float*)d_ws + WS_HIST);
    unsigned* ccnt   = (unsigned*)((float*)d_ws + WS_CCNT);
    unsigned long long* cand = (unsigned long long*)((float*)d_ws + WS_CAND);
    float*    boxes6 = (float*)d_ws + WS_BOX6;
    unsigned long long* gmrow = (unsigned long long*)((float*)d_ws + WS_MROW);
    _Float16* pHi    = use_prep ? (_Float16*)((float*)d_ws + WS_PHI) : nullptr;
    _Float16* pLo    = use_prep ? (_Float16*)((float*)d_ws + WS_PLO) : nullptr;
    float*    zeroPg = use_prep ? ((float*)d_ws + WS_ZERO) : nullptr;
    float*    outp   = (float*)d_out;

    const int prepBlocks = use_prep ? 2048 : 0;
    prep_all<<<dim3(prepBlocks + 256 + 33), dim3(256), 0, stream>>>(
        feat, convw, pHi, pLo, whi, wlo, zeroPg, ghist, prepBlocks);
    conv_mfma<<<dim3(256), dim3(512), 0, stream>>>(feat, convb, whi, wlo, clsw, bboxw,
                                                   clsb, bboxb, pHi, pLo, zeroPg, ghist,
                                                   scores, deltas);
    filter_kernel<<<dim3(256), dim3(256), 0, stream>>>(scores, ghist, ccnt, cand);
    rank_kernel<<<dim3(128), dim3(256), 0, stream>>>(ccnt, cand, deltas, imh, imw, boxes6);
    nmsmask_kernel<<<dim3(40), dim3(256), 0, stream>>>(ccnt, boxes6, gmrow);
    post_kernel<<<dim3(BB), dim3(1024), 0, stream>>>(scores, deltas, ccnt, boxes6, gmrow,
                                                     imh, imw, outp);
}

// Round 10
// 358.373 us; speedup vs baseline: 1.4850x; 1.1027x over previous
//
#include <hip/hip_runtime.h>
#include <cstdint>
#include <cstddef>

#define BB 4
#define CIN 256
#define HH 128
#define WW 128
#define NANCH (HH*WW*9)    // 147456
#define PRE_K 600
#define POST_K 100
#define NMS_T 0.7f
#define CAND_CAP 8192
#define CCNT_STRIDE 16     // one 64B cacheline per image counter

typedef _Float16 f16x8 __attribute__((ext_vector_type(8)));
typedef float    f32x4 __attribute__((ext_vector_type(4)));

// ws layout (float units)
#define WS_SCORES 0                               // f32 [BB*NANCH]
#define WS_DELTAS (BB*NANCH)                      // f32 [BB*NANCH*4]
#define WS_WHI    (WS_DELTAS + BB*NANCH*4)        // fp16 [9][8][256][32]
#define WS_WLO    (WS_WHI + 9*256*128)
#define WS_HIST   (WS_WLO + 9*256*128)            // u32 [BB][2048]
#define WS_CCNT   (WS_HIST + 8192)                // u32 [BB*16] (padded)
#define WS_CAND   (WS_CCNT + 64)                  // u64 [BB][8192]
#define WS_BOX6   (WS_CAND + BB*CAND_CAP*2)       // f32 [BB][600][4]
#define WS_MROW   (WS_BOX6 + BB*PRE_K*4)          // u64 [BB][600][10]
#define WS_PHI    (WS_MROW + BB*PRE_K*10*2)       // fp16 hi plane [4][8][128][128][4x16B]
#define WS_PLANE_F 8388608
#define WS_PLO    (WS_PHI + WS_PLANE_F)
#define WS_ZERO   (WS_PLO + WS_PLANE_F)           // 64B zero page
#define WS_TOTAL_FULL (WS_ZERO + 16)
#define WS_TOTAL_MIN  WS_PHI

__device__ inline unsigned score_key(float f) {
    unsigned u = __float_as_uint(f);
    return (u & 0x80000000u) ? ~u : (u | 0x80000000u);
}

// decode one box (exact float-op order shared by rank fast path and post fallback)
__device__ inline void decode_box(unsigned idx, const float* __restrict__ deltas,
                                  int b, float fw, float fh, float* o4)
{
    const int a   = (int)(idx % 9u);
    const int n4  = (int)(idx / 9u);
    const int hh_ = n4 >> 7;
    const int ww_ = n4 & 127;
    const int si_ = a / 3, ri = a % 3;
    const double sq = (ri == 0) ? 0.70710678118654752440 : ((ri == 1) ? 1.0 : 1.41421356237309504880);
    const double sc = (si_ == 0) ? 8.0 : ((si_ == 1) ? 16.0 : 32.0);
    const float half_w = (float)(16.0 * sc * sq * 0.5);
    const float half_h = (float)(16.0 * sc / sq * 0.5);
    const float shx = 16.f * (float)ww_;
    const float shy = 16.f * (float)hh_;
    const float x1a = shx - half_w, x2a = shx + half_w;
    const float y1a = shy - half_h, y2a = shy + half_h;
    const float aw = x2a - x1a, ah = y2a - y1a;
    const float acx = x1a + 0.5f*aw, acy = y1a + 0.5f*ah;
    const float* d = deltas + ((size_t)b*NANCH + idx) * 4;
    const float dx = d[0], dy = d[1], dw = d[2], dh = d[3];
    const float pcx = acx + dx*aw;
    const float pcy = acy + dy*ah;
    const float pw  = aw * expf(dw);
    const float ph  = ah * expf(dh);
    o4[0] = fminf(fmaxf(pcx - 0.5f*pw, 0.f), fw);
    o4[1] = fminf(fmaxf(pcy - 0.5f*ph, 0.f), fh);
    o4[2] = fminf(fmaxf(pcx + 0.5f*pw, 0.f), fw);
    o4[3] = fminf(fmaxf(pcy + 0.5f*ph, 0.f), fh);
}

// ---------------------------------------------------------------------------
// Kernel 0 (merged prep): [0,prepBlocks) feature planes; [.., +256) weight
// split; [.., +33) zero histogram + candidate counters.
// ---------------------------------------------------------------------------
__global__ __launch_bounds__(256)
void prep_all(const float* __restrict__ feat, const float* __restrict__ convw,
              _Float16* __restrict__ pHi, _Float16* __restrict__ pLo,
              _Float16* __restrict__ whi, _Float16* __restrict__ wlo,
              float* __restrict__ zeroPg, unsigned* __restrict__ ghist,
              int prepBlocks)
{
    const int blk = blockIdx.x;
    if (blk < prepBlocks) {
        const int id = blk * 256 + threadIdx.x;      // 524288 = 4*8*128*128
        if (blk == 0 && threadIdx.x < 16) zeroPg[threadIdx.x] = 0.f;
        const int gx = id & 127;
        const int gy = (id >> 7) & 127;
        const int ck = (id >> 14) & 7;
        const int b  = id >> 17;
        const int g  = (((gx + 1) >> 1) & 1) | (((gy + 1) & 1) << 1);
        const float* fb = feat + ((size_t)(b*256 + ck*32) << 14) + (gy << 7) + gx;
        f16x8 gh[4], gl[4];
        #pragma unroll
        for (int icg = 0; icg < 4; ++icg)
            #pragma unroll
            for (int k = 0; k < 8; ++k) {
                const float v = fb[(size_t)(icg*8 + k) << 14] * 16.f;
                const _Float16 h = (_Float16)v;
                gh[icg][k] = h;
                gl[icg][k] = (_Float16)(v - (float)h);
            }
        char* Hc = (char*)pHi + (size_t)id * 64;
        char* Lc = (char*)pLo + (size_t)id * 64;
        #pragma unroll
        for (int icg = 0; icg < 4; ++icg) {
            const int p = icg ^ g;
            *(f16x8*)(Hc + p*16) = gh[icg];
            *(f16x8*)(Lc + p*16) = gl[icg];
        }
    } else if (blk < prepBlocks + 256) {
        const int g = (blk - prepBlocks) * 256 + threadIdx.x;  // oc*256+ic
        if (g >= 65536) return;
        const int oc = g >> 8, ic = g & 255;
        const int chunk = ic >> 5, icl = ic & 31;
        #pragma unroll
        for (int t = 0; t < 9; ++t) {
            const float v = convw[(size_t)g*9 + t] * 64.f;
            const _Float16 h = (_Float16)v;
            const _Float16 lo = (_Float16)(v - (float)h);
            const size_t o = (size_t)((t*8 + chunk)*256 + oc)*32 + icl;
            whi[o] = h;
            wlo[o] = lo;
        }
    } else {
        const int id = (blk - prepBlocks - 256) * 256 + threadIdx.x;
        if (id < 8256) ghist[id] = 0u;   // hist[8192] + ccnt[64]
    }
}

// ---------------------------------------------------------------------------
// Kernel 1: 3x3 conv 256ic->256oc via MFMA f16 hi/lo split (3-term fp32 emu)
// + bias + ReLU + fused 1x1 heads (head biases folded) + per-image coarse
// score histogram. Block: 512 thr / 8 waves; tile 256 oc x 256 px; grid 256.
// NOTE: t-loop kept at "#pragma unroll 3" with inline address math — full
// unroll + precomputed address arrays caused scratch spills (round 7:
// WRITE_SIZE 12->108 MB, conv 210->310 us). Register budget is exactly
// 2 waves/SIMD (128 acc + 128 rest); don't widen live ranges here.
// ---------------------------------------------------------------------------
__global__ __launch_bounds__(512, 2)
void conv_mfma(const float* __restrict__ feat, const float* __restrict__ convb,
               const _Float16* __restrict__ whi, const _Float16* __restrict__ wlo,
               const float* __restrict__ clsw, const float* __restrict__ bboxw,
               const float* __restrict__ clsb, const float* __restrict__ bboxb,
               const _Float16* __restrict__ pHi, const _Float16* __restrict__ pLo,
               const float* __restrict__ zeroPg, unsigned* __restrict__ ghist,
               float* __restrict__ scores, float* __restrict__ deltas)
{
    // conv phase: halo hi[2] @0/21504, lo[2] @43008/64512; bias @86016 (1KB)
    // epilogue:   sW15 @0 (15360 B), sPart @15360 (61440 B), sHist @76800 (8KB)
    __shared__ __align__(16) unsigned char smem[87040];
    float* sBias = (float*)(smem + 86016);

    const int bid = blockIdx.x;                 // 256 = b(4) x ty(8) x tx(8)
    const int b  = bid >> 6;
    const int ty = (bid >> 3) & 7;
    const int tx = bid & 7;
    const int h0 = ty*16, c0 = tx*16;
    const int tid = threadIdx.x;
    const int w   = tid >> 6;                   // wave 0..7
    const int wm  = w >> 1;                     // oc quadrant
    const int wph = w & 1;                      // px half (rows 0-7 / 8-15)
    const int l  = tid & 63;
    const int q  = l >> 4;                      // lane k-group
    const int c  = l & 15;                      // lane row/col within fragment

    const float* featb = feat + (size_t)b*CIN*HH*WW;
    const int wOff = (wm*64 + c)*32 + q*8;      // A-slab per-lane offset (f16)

    if (tid < 256) sBias[tid] = convb[tid] * 1024.f;

    // chunk-invariant stage descriptors
    int sdesc[3];
    #pragma unroll
    for (int it = 0; it < 3; ++it) {
        const int e = it*512 + tid;
        if (e < 1344) {                         // 1344 = 21*64, wave-uniform
            const int Yl = e / 72, rem = e - Yl*72;
            const int Xl = rem >> 2, p = rem & 3;
            const int gy = h0 - 1 + Yl, gx = c0 - 1 + Xl;
            sdesc[it] = (((unsigned)gy < 128u) && ((unsigned)gx < 128u))
                        ? ((((gy << 7) + gx) << 6) + (p << 4)) : -1;
        } else sdesc[it] = -2;
    }

    auto stage = [&](int ck, int buf) {
        unsigned char* hb = smem + buf*21504;
        unsigned char* lb = smem + 43008 + buf*21504;
        if (pHi) {
            const size_t pb = ((size_t)(b*8 + ck)) << 20;   // 1 MiB per (b,ck)
            #pragma unroll
            for (int pl = 0; pl < 2; ++pl) {
                const char* Ps = (const char*)(pl ? pLo : pHi) + pb;
                unsigned char* Pd = pl ? lb : hb;
                #pragma unroll
                for (int it = 0; it < 3; ++it) {
                    if (sdesc[it] != -2) {
                        const char* src = (sdesc[it] >= 0) ? Ps + sdesc[it]
                                                           : (const char*)zeroPg;
                        __builtin_amdgcn_global_load_lds(
                            (const __attribute__((address_space(1))) void*)src,
                            (__attribute__((address_space(3))) void*)(Pd + it*8192 + tid*16),
                            16, 0, 0);
                    }
                }
            }
        } else {
            const int ic0s = ck*32;
            for (int e = tid; e < 1296; e += 512) {
                const int icg = e / 324, s = e - icg*324;
                const int Y = s / 18, X = s - Y*18;
                const int gy = h0 - 1 + Y, gx = c0 - 1 + X;
                const int g = ((X >> 1) & 1) | ((Y & 1) << 1);
                const bool inb = ((unsigned)gy < 128u) && ((unsigned)gx < 128u);
                f16x8 hv, lv;
                #pragma unroll
                for (int k = 0; k < 8; ++k) {
                    float v = 0.f;
                    if (inb) v = featb[((size_t)(ic0s + icg*8 + k)*HH + gy)*WW + gx];
                    v *= 16.f;
                    const _Float16 h = (_Float16)v;
                    hv[k] = h;
                    lv[k] = (_Float16)(v - (float)h);
                }
                const int base = s*64 + ((icg ^ g) << 4);
                *(f16x8*)(hb + base) = hv;
                *(f16x8*)(lb + base) = lv;
            }
        }
    };

    stage(0, 0);
    __syncthreads();

    f32x4 acc[4][8];
    #pragma unroll
    for (int mf = 0; mf < 4; ++mf) {
        const f32x4 bv = *(const f32x4*)(sBias + (wm*64 + mf*16 + 4*q));
        #pragma unroll
        for (int nf = 0; nf < 8; ++nf) acc[mf][nf] = bv;
    }

    for (int chunk = 0; chunk < 8; ++chunk) {
        const int cur = chunk & 1;
        if (chunk + 1 < 8) stage(chunk + 1, cur ^ 1);   // async, overlaps t-loop
        const unsigned char* hb = smem + cur*21504;
        const unsigned char* lb = smem + 43008 + cur*21504;

        #pragma unroll 3
        for (int t = 0; t < 9; ++t) {
            const int ky = t / 3, kx = t - ky*3;
            const _Float16* pWh = whi + (size_t)(t*8 + chunk)*8192 + wOff;
            const _Float16* pWl = wlo + (size_t)(t*8 + chunk)*8192 + wOff;
            f16x8 ah[4], al[4];
            #pragma unroll
            for (int mf = 0; mf < 4; ++mf) {
                ah[mf] = *(const f16x8*)(const void*)(pWh + mf*512);
                al[mf] = *(const f16x8*)(const void*)(pWl + mf*512);
            }
            #pragma unroll
            for (int nfh = 0; nfh < 2; ++nfh) {
                f16x8 bh[4], bl[4];
                #pragma unroll
                for (int j = 0; j < 4; ++j) {
                    const int nf = nfh*4 + j;
                    const int Y = wph*8 + (nf >> 1)*2 + (c >> 3) + ky;
                    const int X = (nf & 1)*8 + (c & 7) + kx;
                    const int g = ((X >> 1) & 1) | ((Y & 1) << 1);
                    const int addr = (Y*18 + X)*64 + ((q ^ g) << 4);
                    bh[j] = *(const f16x8*)(hb + addr);
                    bl[j] = *(const f16x8*)(lb + addr);
                }
                #pragma unroll
                for (int mf = 0; mf < 4; ++mf)
                    #pragma unroll
                    for (int j = 0; j < 4; ++j) {
                        acc[mf][nfh*4+j] = __builtin_amdgcn_mfma_f32_16x16x32_f16(ah[mf], bh[j], acc[mf][nfh*4+j], 0, 0, 0);
                        acc[mf][nfh*4+j] = __builtin_amdgcn_mfma_f32_16x16x32_f16(ah[mf], bl[j], acc[mf][nfh*4+j], 0, 0, 0);
                        acc[mf][nfh*4+j] = __builtin_amdgcn_mfma_f32_16x16x32_f16(al[mf], bh[j], acc[mf][nfh*4+j], 0, 0, 0);
                    }
            }
        }
        __syncthreads();
    }

    // ---- epilogue: t = relu(acc)/1024, head fold, score histogram ----
    #pragma unroll
    for (int mf = 0; mf < 4; ++mf)
        #pragma unroll
        for (int nf = 0; nf < 8; ++nf)
            #pragma unroll
            for (int r = 0; r < 4; ++r)
                acc[mf][nf][r] = fmaxf(acc[mf][nf][r], 0.f) * 0.0009765625f;

    float*    sW15  = (float*)smem;              // [15][256] f32
    float*    sPart = (float*)(smem + 15360);    // [8 w][15][128 px] f32
    unsigned* sHist = (unsigned*)(smem + 76800); // [2048] u32

    for (int e = tid; e < 2048; e += 512) sHist[e] = 0u;

    for (int g = 0; g < 3; ++g) {
        __syncthreads();
        for (int e = tid; e < 3840; e += 512) {
            const int chl = e >> 8, o = e & 255;
            const int ch = g*15 + chl;
            sW15[e] = (ch < 9) ? clsw[ch*256 + o] : bboxw[(ch - 9)*256 + o];
        }
        __syncthreads();
        for (int chl = 0; chl < 15; ++chl) {
            f32x4 wv[4];
            #pragma unroll
            for (int mf = 0; mf < 4; ++mf)
                wv[mf] = *(const f32x4*)(sW15 + chl*256 + wm*64 + mf*16 + 4*q);
            float p[8];
            #pragma unroll
            for (int nf = 0; nf < 8; ++nf) {
                float s = 0.f;
                #pragma unroll
                for (int mf = 0; mf < 4; ++mf)
                    #pragma unroll
                    for (int r = 0; r < 4; ++r)
                        s += wv[mf][r] * acc[mf][nf][r];
                s += __shfl_xor(s, 16, 64);
                s += __shfl_xor(s, 32, 64);
                p[nf] = s;
            }
            const float v0 = (q == 0) ? p[0] : (q == 1) ? p[1] : (q == 2) ? p[2] : p[3];
            const float v1 = (q == 0) ? p[4] : (q == 1) ? p[5] : (q == 2) ? p[6] : p[7];
            sPart[(w*15 + chl)*128 + q*16 + c]      = v0;
            sPart[(w*15 + chl)*128 + 64 + q*16 + c] = v1;
        }
        __syncthreads();
        for (int e = tid; e < 3840; e += 512) {
            const int chl = e >> 8, pxg = e & 255;
            const int ph = pxg >> 7, pxl = pxg & 127;
            float s = 0.f;
            #pragma unroll
            for (int wmq = 0; wmq < 4; ++wmq)
                s += sPart[((wmq*2 + ph)*15 + chl)*128 + pxl];
            const int ch = g*15 + chl;
            s += (ch < 9) ? clsb[ch] : bboxb[ch - 9];
            const int nf = pxl >> 4, cc2 = pxl & 15;
            const int Y = ph*8 + (nf >> 1)*2 + (cc2 >> 3);
            const int X = (nf & 1)*8 + (cc2 & 7);
            const int gy = h0 + Y, gx = c0 + X;
            const int n4 = gy*WW + gx;
            if (ch < 9) {
                scores[(size_t)b*NANCH + n4*9 + ch] = s;
                atomicAdd(&sHist[score_key(s) >> 21], 1u);
            } else {
                const int cc = ch - 9;
                deltas[((size_t)b*NANCH + n4*9 + (cc >> 2))*4 + (cc & 3)] = s;
            }
        }
    }
    // merge block-local histogram (integer counts -> deterministic)
    for (int e = tid; e < 2048; e += 512) {
        const unsigned cv = sHist[e];
        if (cv) atomicAdd(&ghist[b*2048 + e], cv);
    }
}

// ---------------------------------------------------------------------------
// find_thresh: wave-0 parallel threshold search over a histogram.
// ---------------------------------------------------------------------------
__device__ inline void find_thresh(const unsigned* hist, int NB, unsigned target, unsigned* shv)
{
    const int tid = threadIdx.x;
    if (tid < 64) {
        const int gsz = NB >> 5;                  // 64 or 32
        unsigned gsum = 0;
        if (tid < 32)
            for (int k = 0; k < gsz; ++k)
                gsum += hist[tid*gsz + ((k + tid) & (gsz-1))];
        unsigned suf = gsum;
        #pragma unroll
        for (int d = 1; d < 32; d <<= 1) {
            const unsigned t = __shfl_down(suf, d, 64);
            if (tid + d < 32) suf += t;
        }
        const unsigned long long m = __ballot(tid < 32 && suf >= target);
        const int G = 63 - __clzll(m);
        unsigned caboveG = 0;
        { const unsigned t = __shfl(suf, G+1, 64); if (G < 31) caboveG = t; }
        unsigned h = 0;
        if (tid < gsz) h = hist[G*gsz + tid];
        unsigned wsuf = h;
        #pragma unroll
        for (int d = 1; d < 64; d <<= 1) {
            const unsigned t = __shfl_down(wsuf, d, 64);
            if (tid + d < gsz) wsuf += t;
        }
        const unsigned long long m2 = __ballot(tid < gsz && (caboveG + wsuf) >= target);
        const int L = 63 - __clzll(m2);
        if (tid == L) { shv[0] = (unsigned)(G*gsz + L); shv[1] = caboveG + wsuf - h; }
    }
}

// ---------------------------------------------------------------------------
// Kernel F: wide candidate filter. 256 blocks; block = (image, slice of 2304).
// LDS-compacts its slice's candidates, then reserves a contiguous range with
// ONE global atomic per block (padded per-image counters) and writes out
// coalesced. Result set identical (rank_kernel is order-independent).
// ---------------------------------------------------------------------------
__global__ __launch_bounds__(256)
void filter_kernel(const float* __restrict__ scores, const unsigned* __restrict__ ghist,
                   unsigned* __restrict__ ccnt, unsigned long long* __restrict__ cand)
{
    __shared__ unsigned h[2048];
    __shared__ unsigned shv[8];
    __shared__ unsigned long long lbuf[2304];
    __shared__ unsigned lcnt, gbase;
    const int blk = blockIdx.x;         // 256 = b(4) x s(64)
    const int b = blk >> 6, s = blk & 63;
    const int tid = threadIdx.x;
    const unsigned* hb = ghist + b*2048;
    if (tid == 0) lcnt = 0u;
    for (int e = tid; e < 2048; e += 256) h[e] = hb[e];
    __syncthreads();
    find_thresh(h, 2048, PRE_K, shv);
    __syncthreads();
    const unsigned T1 = shv[0];
    const unsigned C  = shv[1] + h[T1];     // count(>= T1) >= 600
    const float* si = scores + (size_t)b*NANCH + s*2304;
    if (C <= (unsigned)CAND_CAP) {
        #pragma unroll
        for (int k = 0; k < 9; ++k) {
            const int i = tid + k*256;
            const unsigned u = score_key(si[i]);
            if ((u >> 21) >= T1) {
                const unsigned p = atomicAdd(&lcnt, 1u);     // LDS atomic
                lbuf[p] = ((unsigned long long)(~u) << 32) | (unsigned)(s*2304 + i);
            }
        }
        __syncthreads();
        if (tid == 0) gbase = atomicAdd(&ccnt[b*CCNT_STRIDE], lcnt);  // 1 global atomic
        __syncthreads();
        const unsigned nL = lcnt, base = gbase;
        for (unsigned e = tid; e < nL; e += 256)
            cand[(size_t)b*CAND_CAP + base + e] = lbuf[e];
    } else if (s == 0 && tid == 0) {
        ccnt[b*CCNT_STRIDE] = 0x7FFFFFFFu;   // overflow -> post fallback
    }
}

// ---------------------------------------------------------------------------
// Kernel R: wide rank-by-counting selection + decode. Keys (~u)<<32|idx are
// unique -> rank = #{cv2 < cv} is exact score-desc/index-asc order. Threads
// with rank < 600 decode their box straight into boxes600[b][rank].
// Grid 4 images x 32 slices of 256.
// ---------------------------------------------------------------------------
__global__ __launch_bounds__(256)
void rank_kernel(const unsigned* __restrict__ ccnt, const unsigned long long* __restrict__ cand,
                 const float* __restrict__ deltas,
                 const int* __restrict__ imh, const int* __restrict__ imw,
                 float* __restrict__ boxes6)
{
    __shared__ unsigned long long cnd[CAND_CAP];   // 64 KB
    const int blk = blockIdx.x;          // 128 = b(4) x s(32)
    const int b = blk >> 5, s = blk & 31;
    const int tid = threadIdx.x;
    const unsigned n = ccnt[b*CCNT_STRIDE];
    if (n > (unsigned)CAND_CAP) return;            // fallback handled in post
    const int e0 = s*256;
    if ((unsigned)e0 >= n) return;
    for (int e = tid; e < (int)n; e += 256)
        cnd[e] = cand[(size_t)b*CAND_CAP + e];
    __syncthreads();
    const int e = e0 + tid;
    if (e >= (int)n) return;
    const unsigned long long cv = cnd[e];
    unsigned rank = 0;
    for (int e2 = 0; e2 < (int)n; ++e2)
        rank += (cnd[e2] < cv) ? 1u : 0u;
    if (rank < PRE_K) {
        float o4[4];
        decode_box((unsigned)cv, deltas, b, (float)imw[0], (float)imh[0], o4);
        float* o = boxes6 + ((size_t)b*PRE_K + rank)*4;
        o[0] = o4[0]; o[1] = o4[1]; o[2] = o4[2]; o[3] = o4[3];
    }
}

// ---------------------------------------------------------------------------
// Kernel M: wide NMS suppression-mask build. Grid 4 images x 10 row-groups
// (60 rows x 10 words each). Writes gmrow[b][600][10].
// ---------------------------------------------------------------------------
__global__ __launch_bounds__(256)
void nmsmask_kernel(const unsigned* __restrict__ ccnt, const float* __restrict__ boxes6,
                    unsigned long long* __restrict__ gmrow)
{
    __shared__ float bx[PRE_K][4];
    const int blk = blockIdx.x;          // 40 = b(4) x rg(10)
    const int b = blk / 10, rg = blk - b*10;
    const int tid = threadIdx.x;
    const unsigned n = ccnt[b*CCNT_STRIDE];
    if (n > (unsigned)CAND_CAP) return;            // fallback handled in post
    for (int e = tid; e < PRE_K*4; e += 256)
        bx[e >> 2][e & 3] = boxes6[(size_t)b*PRE_K*4 + e];
    __syncthreads();
    for (int item = tid; item < 600; item += 256) {  // 60 rows x 10 words
        const int i  = rg*60 + item/10;
        const int wj = item - (item/10)*10;
        unsigned long long m = 0ull;
        const int jbase = wj * 64;
        if (jbase + 63 > i) {
            const float xi1 = bx[i][0], yi1 = bx[i][1], xi2 = bx[i][2], yi2 = bx[i][3];
            const float ai = (xi2 - xi1) * (yi2 - yi1);
            for (int bit = 0; bit < 64; ++bit) {
                const int j = jbase + bit;
                if (j < PRE_K && j > i) {
                    const float xx1 = fmaxf(xi1, bx[j][0]);
                    const float yy1 = fmaxf(yi1, bx[j][1]);
                    const float xx2 = fminf(xi2, bx[j][2]);
                    const float yy2 = fminf(yi2, bx[j][3]);
                    const float inter = fmaxf(xx2 - xx1, 0.f) * fmaxf(yy2 - yy1, 0.f);
                    const float aj = (bx[j][2] - bx[j][0]) * (bx[j][3] - bx[j][1]);
                    const float iou = inter / (ai + aj - inter);
                    if (iou > NMS_T) m |= (1ull << bit);
                }
            }
        }
        gmrow[((size_t)b*PRE_K + i)*10 + wj] = m;
    }
}

// ---------------------------------------------------------------------------
// Kernel 2 (post): fast path = load precomputed boxes+mask, serial keep-scan,
// compact, write top-100. Fallback (n > CAND_CAP, never on bench data) =
// full exact 3-pass radix over global scores + sorts + decode + mask.
// ---------------------------------------------------------------------------
__device__ inline unsigned long long shfl_u64(unsigned long long v, int src) {
    const int lo = __shfl((int)(v & 0xffffffffull), src, 64);
    const int hi = __shfl((int)(v >> 32), src, 64);
    return ((unsigned long long)(unsigned)hi << 32) | (unsigned)lo;
}

__global__ __launch_bounds__(1024)
void post_kernel(const float* __restrict__ scores, const float* __restrict__ deltas,
                 const unsigned* __restrict__ ccnt,
                 const float* __restrict__ boxes6, const unsigned long long* __restrict__ gmrow,
                 const int* __restrict__ imh, const int* __restrict__ imw,
                 float* __restrict__ out)
{
    __shared__ unsigned hist[2048];
    __shared__ unsigned long long arr[1024];
    __shared__ unsigned tiebuf[1024];
    __shared__ unsigned shv[8];
    __shared__ float bx[PRE_K][4];
    __shared__ unsigned long long mrow[PRE_K][10];
    __shared__ unsigned long long keepw[10];
    __shared__ unsigned wpfx[11];
    __shared__ int sel[POST_K];
    const int b = blockIdx.x, tid = threadIdx.x;
    const float* si = scores + (size_t)b*NANCH;

    const unsigned n = ccnt[b*CCNT_STRIDE];
    const bool fast = (n <= (unsigned)CAND_CAP);

    if (fast) {
        // ===== fast path: everything precomputed by rank/nmsmask =====
        for (int e = tid; e < PRE_K*4; e += 1024)
            bx[e >> 2][e & 3] = boxes6[(size_t)b*PRE_K*4 + e];
        for (int e = tid; e < PRE_K*10; e += 1024)
            mrow[e/10][e - (e/10)*10] = gmrow[(size_t)b*PRE_K*10 + e];
        __syncthreads();
    } else {
        // ===== fallback: exact full-scan selection =====
        for (int i = tid; i < 2048; i += 1024) hist[i] = 0;
        __syncthreads();
        for (int i = tid; i < NANCH; i += 1024)
            atomicAdd(&hist[score_key(si[i]) >> 21], 1u);
        __syncthreads();
        find_thresh(hist, 2048, PRE_K, shv);
        __syncthreads();
        const unsigned T1 = shv[0], gtA = shv[1];
        __syncthreads();

        for (int i = tid; i < 2048; i += 1024) hist[i] = 0;
        __syncthreads();
        for (int i = tid; i < NANCH; i += 1024) {
            const unsigned u = score_key(si[i]);
            if ((u >> 21) == T1) atomicAdd(&hist[(u >> 10) & 0x7FFu], 1u);
        }
        __syncthreads();
        find_thresh(hist, 2048, PRE_K - gtA, shv);
        __syncthreads();
        const unsigned T2 = shv[0], gtB = shv[1];
        const unsigned top22 = (T1 << 11) | T2;
        __syncthreads();

        for (int i = tid; i < 1024; i += 1024) hist[i] = 0;
        __syncthreads();
        for (int i = tid; i < NANCH; i += 1024) {
            const unsigned u = score_key(si[i]);
            if ((u >> 10) == top22) atomicAdd(&hist[u & 0x3FFu], 1u);
        }
        __syncthreads();
        find_thresh(hist, 1024, PRE_K - gtA - gtB, shv);
        if (tid == 0) { shv[4] = 0; shv[5] = 0; }
        __syncthreads();
        const unsigned u_thr = (top22 << 10) | shv[0];
        const unsigned n_greater = gtA + gtB + shv[1];
        __syncthreads();

        for (int i = tid; i < NANCH; i += 1024) {
            const unsigned u = score_key(si[i]);
            if (u > u_thr) {
                const unsigned p = atomicAdd(&shv[4], 1u);
                arr[p] = ((unsigned long long)(~u) << 32) | (unsigned)i;
            } else if (u == u_thr) {
                const unsigned p = atomicAdd(&shv[5], 1u);
                if (p < 1024u) tiebuf[p] = (unsigned)i;
            }
        }
        __syncthreads();
        const unsigned cnt_tie = (shv[5] > 1024u) ? 1024u : shv[5];
        if ((unsigned)tid >= cnt_tie) tiebuf[tid] = 0xFFFFFFFFu;

        for (unsigned k = 2; k <= 1024; k <<= 1)
            for (unsigned j = k >> 1; j > 0; j >>= 1) {
                __syncthreads();
                const unsigned i = (unsigned)tid, ixj = i ^ j;
                if (ixj > i) {
                    const unsigned a = tiebuf[i], cc = tiebuf[ixj];
                    if ((a > cc) == ((i & k) == 0)) { tiebuf[i] = cc; tiebuf[ixj] = a; }
                }
            }
        __syncthreads();
        const unsigned ties_needed = PRE_K - n_greater;
        if ((unsigned)tid < ties_needed)
            arr[n_greater + tid] = ((unsigned long long)(~u_thr) << 32) | tiebuf[tid];
        if (tid >= PRE_K) arr[tid] = ~0ull;

        for (unsigned k = 2; k <= 1024; k <<= 1)
            for (unsigned j = k >> 1; j > 0; j >>= 1) {
                __syncthreads();
                const unsigned i = (unsigned)tid, ixj = i ^ j;
                if (ixj > i) {
                    const unsigned long long a = arr[i], cc = arr[ixj];
                    if ((a > cc) == ((i & k) == 0)) { arr[i] = cc; arr[ixj] = a; }
                }
            }
        __syncthreads();

        // decode into LDS
        if (tid < PRE_K) {
            float o4[4];
            decode_box((unsigned)arr[tid], deltas, b, (float)imw[0], (float)imh[0], o4);
            bx[tid][0] = o4[0]; bx[tid][1] = o4[1]; bx[tid][2] = o4[2]; bx[tid][3] = o4[3];
        }
        __syncthreads();

        // mask build
        for (int item = tid; item < PRE_K*10; item += 1024) {
            const int i  = item / 10;
            const int wj = item - i*10;
            unsigned long long m = 0ull;
            const int jbase = wj * 64;
            if (jbase + 63 > i) {
                const float xi1 = bx[i][0], yi1 = bx[i][1], xi2 = bx[i][2], yi2 = bx[i][3];
                const float ai = (xi2 - xi1) * (yi2 - yi1);
                for (int bit = 0; bit < 64; ++bit) {
                    const int j = jbase + bit;
                    if (j < PRE_K && j > i) {
                        const float xx1 = fmaxf(xi1, bx[j][0]);
                        const float yy1 = fmaxf(yi1, bx[j][1]);
                        const float xx2 = fminf(xi2, bx[j][2]);
                        const float yy2 = fminf(yi2, bx[j][3]);
                        const float inter = fmaxf(xx2 - xx1, 0.f) * fmaxf(yy2 - yy1, 0.f);
                        const float aj = (bx[j][2] - bx[j][0]) * (bx[j][3] - bx[j][1]);
                        const float iou = inter / (ai + aj - inter);
                        if (iou > NMS_T) m |= (1ull << bit);
                    }
                }
            }
            mrow[i][wj] = m;
        }
        __syncthreads();
    }

    // ===== serial keep-scan (wave 0), compaction, output =====
    if (tid < 64) {
        const int lane = tid;
        unsigned long long kwv;
        if (lane < 9)       kwv = ~0ull;
        else if (lane == 9) kwv = (1ull << (PRE_K - 576)) - 1;
        else                kwv = 0ull;
        for (int w = 0; w < 10; ++w) {
            const int base = w*64;
            const int nb = (w == 9) ? (PRE_K - 576) : 64;
            if (lane == w) {
                for (int bit = 0; bit < nb; ++bit) {
                    const unsigned long long mm = mrow[base + bit][w];
                    if ((kwv >> bit) & 1ull) kwv &= ~mm;
                }
            }
            const unsigned long long fw = shfl_u64(kwv, w);
            if (lane > w && lane < 10) {
                for (int bit = 0; bit < nb; ++bit) {
                    const unsigned long long mm = mrow[base + bit][lane];
                    if ((fw >> bit) & 1ull) kwv &= ~mm;
                }
            }
        }
        if (lane < 10) keepw[lane] = kwv;
    }
    __syncthreads();
    if (tid == 0) {
        unsigned ccount = 0;
        #pragma unroll
        for (int w = 0; w < 10; ++w) { wpfx[w] = ccount; ccount += (unsigned)__popcll(keepw[w]); }
        wpfx[10] = ccount;
    }
    if (tid < POST_K) sel[tid] = -1;
    __syncthreads();
    if (tid < PRE_K) {
        const int w = tid >> 6, bit = tid & 63;
        const unsigned long long kw = keepw[w];
        if ((kw >> bit) & 1ull) {
            const unsigned rank = wpfx[w] + (unsigned)__popcll(kw & ((1ull << bit) - 1ull));
            if (rank < POST_K) sel[rank] = tid;
        }
    }
    __syncthreads();
    if (tid < POST_K) {
        const int s_ = sel[tid];
        float o0 = 0.f, o1 = 0.f, o2 = 0.f, o3 = 0.f;
        if (s_ >= 0) { o0 = bx[s_][0]; o1 = bx[s_][1]; o2 = bx[s_][2]; o3 = bx[s_][3]; }
        float* o = out + (size_t)b*POST_K*4 + tid*4;
        o[0] = o0; o[1] = o1; o[2] = o2; o[3] = o3;
    }
}

// ---------------------------------------------------------------------------
extern "C" void kernel_launch(void* const* d_in, const int* in_sizes, int n_in,
                              void* d_out, int out_size, void* d_ws, size_t ws_size,
                              hipStream_t stream) {
    const float* feat  = (const float*)d_in[0];
    const float* convw = (const float*)d_in[1];
    const float* convb = (const float*)d_in[2];
    const float* clsw  = (const float*)d_in[3];
    const float* clsb  = (const float*)d_in[4];
    const float* bboxw = (const float*)d_in[5];
    const float* bboxb = (const float*)d_in[6];
    const int*   imh   = (const int*)d_in[7];
    const int*   imw   = (const int*)d_in[8];

    if (ws_size < (size_t)WS_TOTAL_MIN * sizeof(float)) return;
    const bool use_prep = ws_size >= (size_t)WS_TOTAL_FULL * sizeof(float);

    float*    scores = (float*)d_ws + WS_SCORES;
    float*    deltas = (float*)d_ws + WS_DELTAS;
    _Float16* whi    = (_Float16*)((float*)d_ws + WS_WHI);
    _Float16* wlo    = (_Float16*)((float*)d_ws + WS_WLO);
    unsigned* ghist  = (unsigned*)((float*)d_ws + WS_HIST);
    unsigned* ccnt   = (unsigned*)((float*)d_ws + WS_CCNT);
    unsigned long long* cand = (unsigned long long*)((float*)d_ws + WS_CAND);
    float*    boxes6 = (float*)d_ws + WS_BOX6;
    unsigned long long* gmrow = (unsigned long long*)((float*)d_ws + WS_MROW);
    _Float16* pHi    = use_prep ? (_Float16*)((float*)d_ws + WS_PHI) : nullptr;
    _Float16* pLo    = use_prep ? (_Float16*)((float*)d_ws + WS_PLO) : nullptr;
    float*    zeroPg = use_prep ? ((float*)d_ws + WS_ZERO) : nullptr;
    float*    outp   = (float*)d_out;

    const int prepBlocks = use_prep ? 2048 : 0;
    prep_all<<<dim3(prepBlocks + 256 + 33), dim3(256), 0, stream>>>(
        feat, convw, pHi, pLo, whi, wlo, zeroPg, ghist, prepBlocks);
    conv_mfma<<<dim3(256), dim3(512), 0, stream>>>(feat, convb, whi, wlo, clsw, bboxw,
                                                   clsb, bboxb, pHi, pLo, zeroPg, ghist,
                                                   scores, deltas);
    filter_kernel<<<dim3(256), dim3(256), 0, stream>>>(scores, ghist, ccnt, cand);
    rank_kernel<<<dim3(128), dim3(256), 0, stream>>>(ccnt, cand, deltas, imh, imw, boxes6);
    nmsmask_kernel<<<dim3(40), dim3(256), 0, stream>>>(ccnt, boxes6, gmrow);
    post_kernel<<<dim3(BB), dim3(1024), 0, stream>>>(scores, deltas, ccnt, boxes6, gmrow,
                                                     imh, imw, outp);
}